// Round 6
// baseline (353.900 us; speedup 1.0000x reference)
//
#include <hip/hip_runtime.h>
#include <hip/hip_bf16.h>

#define NNODES 20000
#define EEDGES 320000
#define FIN 1024
#define HMID 256
#define DOUT 128
#define ALPHA_BLOCKS ((NNODES + 3) / 4)

typedef __bf16 bf16x8 __attribute__((ext_vector_type(8)));
typedef __bf16 bf16x4 __attribute__((ext_vector_type(4)));
typedef __bf16 bf16x2 __attribute__((ext_vector_type(2)));
typedef float f32x4 __attribute__((ext_vector_type(4)));

typedef const __attribute__((address_space(1))) void* gas_ptr;
typedef __attribute__((address_space(3))) void* las_ptr;
__device__ __forceinline__ void async_copy16(const void* g, void* l) {
    __builtin_amdgcn_global_load_lds((gas_ptr)g, (las_ptr)l, 16, 0, 0);
}

// ---------------- weight prep ----------------
__global__ void k_prep_wgcn(const float* __restrict__ W, __bf16* __restrict__ Wt) {
    int tid = blockIdx.x * 256 + threadIdx.x;
    if (tid >= FIN * HMID) return;
    int k = tid >> 8;
    int n = tid & 255;
    Wt[(size_t)n * FIN + k] = (__bf16)W[tid];
}

__global__ void k_prep_watt(const float* __restrict__ Wq, const float* __restrict__ Wk,
                            const float* __restrict__ Wv, const float* __restrict__ Ws,
                            const float* __restrict__ bq, const float* __restrict__ bk,
                            const float* __restrict__ bv, const float* __restrict__ bs,
                            __bf16* __restrict__ Wallt, float* __restrict__ ball) {
    int g = blockIdx.y;
    const float* W = (g == 0) ? Wq : (g == 1) ? Wk : (g == 2) ? Wv : Ws;
    int tid = blockIdx.x * 256 + threadIdx.x;
    if (tid < HMID * DOUT) {
        int k = tid >> 7;
        int n = tid & 127;
        Wallt[(size_t)(g * DOUT + n) * HMID + k] = (__bf16)W[tid];
    }
    if (tid < DOUT) {
        const float* b = (g == 0) ? bq : (g == 1) ? bk : (g == 2) ? bv : bs;
        ball[g * DOUT + tid] = b[tid];
    }
}

// ---------------- CSR build ----------------
__global__ void k_init(int* __restrict__ cnt, float* __restrict__ S) {
    int i = blockIdx.x * 256 + threadIdx.x;
    if (i < NNODES) cnt[i] = 0;
    if (i < 16) S[i] = 0.0f;
}

__global__ void k_count(const int* __restrict__ dst, int* __restrict__ cnt) {
    int e = blockIdx.x * 256 + threadIdx.x;
    if (e < EEDGES) atomicAdd(&cnt[dst[e]], 1);
}

__global__ void k_dinv(const int* __restrict__ cnt, float* __restrict__ dinv,
                       int* __restrict__ cursor) {
    int i = blockIdx.x * 256 + threadIdx.x;
    if (i < NNODES) {
        dinv[i] = rsqrtf((float)cnt[i] + 1.0f);
        cursor[i] = 0;
    }
}

__global__ __launch_bounds__(1024) void k_scan(const int* __restrict__ cnt,
                                               int* __restrict__ rowptr) {
    __shared__ int sh[1024];
    int t = threadIdx.x;
    int base = t * 20;
    int local[20];
    int sum = 0;
#pragma unroll
    for (int j = 0; j < 20; j++) {
        int i = base + j;
        int v = (i < NNODES) ? cnt[i] : 0;
        local[j] = sum;
        sum += v;
    }
    sh[t] = sum;
    __syncthreads();
    for (int off = 1; off < 1024; off <<= 1) {
        int v = (t >= off) ? sh[t - off] : 0;
        __syncthreads();
        sh[t] += v;
        __syncthreads();
    }
    int prev = (t > 0) ? sh[t - 1] : 0;
#pragma unroll
    for (int j = 0; j < 20; j++) {
        int i = base + j;
        if (i < NNODES) rowptr[i] = prev + local[j];
    }
    if (t == 1023) rowptr[NNODES] = sh[1023];
}

__global__ void k_fill(const int* __restrict__ src, const int* __restrict__ dst,
                       const int* __restrict__ rowptr, int* __restrict__ cursor,
                       const float* __restrict__ dinv,
                       int* __restrict__ srcsorted, float* __restrict__ wsorted) {
    int e = blockIdx.x * 256 + threadIdx.x;
    if (e >= EEDGES) return;
    int d = dst[e];
    int s = src[e];
    int pos = atomicAdd(&cursor[d], 1);
    int w = rowptr[d] + pos;
    srcsorted[w] = s;
    wsorted[w] = dinv[s];
}

// ---------------- GEMM1: h0bf = bf16(x @ W_gcn) ----------------
// 64x256 tile, grid 313x1. Double-buffered LDS, raw s_waitcnt(vmcnt)+s_barrier
// so prefetch loads stay in flight across the barrier (no vmcnt(0) drain).
// As[buf]: [8 kchunk][64 row] x 4 floats.  Bs[buf]: [4 kchunk][256 col] x 8 bf16.
__global__ __launch_bounds__(256) void k_gemm1(const float* __restrict__ x,
                                               const __bf16* __restrict__ Wt,
                                               __bf16* __restrict__ h0bf) {
    __shared__ float As[2][2048];    // 2 x 8 KB
    __shared__ __bf16 Bs[2][8192];   // 2 x 16 KB
    int t = threadIdx.x;
    int lane = t & 63;
    int m = lane & 15, q = lane >> 4;
    int wave = t >> 6;
    int wc = wave * 64;
    int r0 = blockIdx.x * 64;

    // A staging: u = j*256+t, row = u&63, kc = u>>6 (0..7, 4 floats each)
    const float* asrc[2];
    int aoff[2];
#pragma unroll
    for (int j = 0; j < 2; j++) {
        int u = j * 256 + t;
        int row = r0 + (u & 63);
        if (row >= NNODES) row = NNODES - 1;
        asrc[j] = x + (size_t)row * FIN + (u >> 6) * 4;
        aoff[j] = u * 4;
    }
    // B staging: u = j*256+t, col = u&255, kc = u>>8 (0..3, 8 bf16 each)
    const __bf16* bsrc[4];
    int boff[4];
#pragma unroll
    for (int j = 0; j < 4; j++) {
        int u = j * 256 + t;
        bsrc[j] = Wt + (size_t)(u & 255) * FIN + (u >> 8) * 8;
        boff[j] = u * 8;
    }

    f32x4 acc[4][4] = {};
    constexpr int NK = FIN / 32;  // 32 iterations

    // prologue: stage iter 0 into buffer 0
#pragma unroll
    for (int j = 0; j < 2; j++) async_copy16(asrc[j], &As[0][aoff[j]]);
#pragma unroll
    for (int j = 0; j < 4; j++) async_copy16(bsrc[j], &Bs[0][boff[j]]);

#pragma unroll 1
    for (int kk = 0; kk < NK; kk++) {
        int cur = kk & 1;
        if (kk + 1 < NK) {
            int k0 = (kk + 1) * 32;
#pragma unroll
            for (int j = 0; j < 2; j++) async_copy16(asrc[j] + k0, &As[cur ^ 1][aoff[j]]);
#pragma unroll
            for (int j = 0; j < 4; j++) async_copy16(bsrc[j] + k0, &Bs[cur ^ 1][boff[j]]);
            // wait only for current iter's 6 loads (prefetch's 6 stay in flight)
            __builtin_amdgcn_s_waitcnt(0x0F76);  // vmcnt(6), lgkm/exp no-wait
        } else {
            __builtin_amdgcn_s_waitcnt(0x0F70);  // vmcnt(0)
        }
        __builtin_amdgcn_s_barrier();

        bf16x8 af[4], bfr[4];
#pragma unroll
        for (int i = 0; i < 4; i++) {
            int R = i * 16 + m;
            f32x4 a0 = *(const f32x4*)&As[cur][((2 * q) * 64 + R) * 4];
            f32x4 a1 = *(const f32x4*)&As[cur][((2 * q + 1) * 64 + R) * 4];
            bf16x8 a;
            a[0] = (__bf16)a0[0]; a[1] = (__bf16)a0[1]; a[2] = (__bf16)a0[2]; a[3] = (__bf16)a0[3];
            a[4] = (__bf16)a1[0]; a[5] = (__bf16)a1[1]; a[6] = (__bf16)a1[2]; a[7] = (__bf16)a1[3];
            af[i] = a;
        }
#pragma unroll
        for (int jb = 0; jb < 4; jb++) {
            int C = wc + jb * 16 + m;
            bfr[jb] = *(const bf16x8*)&Bs[cur][(q * 256 + C) * 8];
        }
#pragma unroll
        for (int i = 0; i < 4; i++)
#pragma unroll
            for (int jb = 0; jb < 4; jb++)
                acc[i][jb] = __builtin_amdgcn_mfma_f32_16x16x32_bf16(af[i], bfr[jb], acc[i][jb], 0, 0, 0);

        // all waves done reading buffer `cur` before next iter overwrites it
        __builtin_amdgcn_s_barrier();
    }

#pragma unroll
    for (int i = 0; i < 4; i++)
#pragma unroll
        for (int jb = 0; jb < 4; jb++)
#pragma unroll
            for (int r = 0; r < 4; r++) {
                int row = r0 + i * 16 + q * 4 + r;
                int col = wc + jb * 16 + m;
                if (row < NNODES) h0bf[(size_t)row * 256 + col] = (__bf16)acc[i][jb][r];
            }
}

// ---------------- GCN gather (batch-4 MLP) ----------------
__global__ __launch_bounds__(256) void k_gcn_gather(const int* __restrict__ rowptr,
                                                    const int* __restrict__ srcsorted,
                                                    const float* __restrict__ wsorted,
                                                    const __bf16* __restrict__ h0bf,
                                                    const float* __restrict__ dinv,
                                                    const float* __restrict__ bgcn,
                                                    __bf16* __restrict__ hbf) {
    int gid = blockIdx.x * 256 + threadIdx.x;
    int n = gid >> 6, l = gid & 63;
    if (n >= NNODES) return;
    float dn = dinv[n];
    float wn = dn * dn;
    bf16x4 hv = *(const bf16x4*)(h0bf + (size_t)n * 256 + l * 4);
    float4 b = ((const float4*)bgcn)[l];
    float ax = (float)hv[0] * wn + b.x;
    float ay = (float)hv[1] * wn + b.y;
    float az = (float)hv[2] * wn + b.z;
    float aw = (float)hv[3] * wn + b.w;
    int beg = rowptr[n], end = rowptr[n + 1];
    for (int i = beg; i < end; i += 4) {
        int i1 = i + 1 < end ? i + 1 : end - 1;
        int i2 = i + 2 < end ? i + 2 : end - 1;
        int i3 = i + 3 < end ? i + 3 : end - 1;
        int s0 = srcsorted[i], s1 = srcsorted[i1], s2 = srcsorted[i2], s3 = srcsorted[i3];
        float w0 = wsorted[i] * dn;
        float w1 = (i + 1 < end) ? wsorted[i1] * dn : 0.f;
        float w2 = (i + 2 < end) ? wsorted[i2] * dn : 0.f;
        float w3 = (i + 3 < end) ? wsorted[i3] * dn : 0.f;
        bf16x4 v0 = *(const bf16x4*)(h0bf + (size_t)s0 * 256 + l * 4);
        bf16x4 v1 = *(const bf16x4*)(h0bf + (size_t)s1 * 256 + l * 4);
        bf16x4 v2 = *(const bf16x4*)(h0bf + (size_t)s2 * 256 + l * 4);
        bf16x4 v3 = *(const bf16x4*)(h0bf + (size_t)s3 * 256 + l * 4);
        ax += (float)v0[0] * w0 + (float)v1[0] * w1 + (float)v2[0] * w2 + (float)v3[0] * w3;
        ay += (float)v0[1] * w0 + (float)v1[1] * w1 + (float)v2[1] * w2 + (float)v3[1] * w3;
        az += (float)v0[2] * w0 + (float)v1[2] * w1 + (float)v2[2] * w2 + (float)v3[2] * w3;
        aw += (float)v0[3] * w0 + (float)v1[3] * w1 + (float)v2[3] * w2 + (float)v3[3] * w3;
    }
    bf16x4 o;
    o[0] = (__bf16)(ax >= 0.f ? ax : 0.01f * ax);
    o[1] = (__bf16)(ay >= 0.f ? ay : 0.01f * ay);
    o[2] = (__bf16)(az >= 0.f ? az : 0.01f * az);
    o[3] = (__bf16)(aw >= 0.f ? aw : 0.01f * aw);
    *(bf16x4*)(hbf + (size_t)n * 256 + l * 4) = o;
}

// ---------------- GEMM2: q/k/v/s tables = hbf @ Wallt + ball ----------------
__global__ __launch_bounds__(256) void k_gemm2(const __bf16* __restrict__ hbf,
                                               const __bf16* __restrict__ Wallt,
                                               const float* __restrict__ ball,
                                               __bf16* __restrict__ qarr,
                                               __bf16* __restrict__ karr,
                                               __bf16* __restrict__ varr,
                                               __bf16* __restrict__ sarr) {
    __shared__ __bf16 As[4096];
    __shared__ __bf16 Bs[4096];
    int t = threadIdx.x;
    int lane = t & 63;
    int m = lane & 15, q = lane >> 4;
    int wave = t >> 6;
    int wr = (wave & 1) * 64;
    int wc = (wave >> 1) * 64;
    int r0 = blockIdx.x * 128;
    int c0 = blockIdx.y * 128;
    __bf16* tbl = (blockIdx.y == 0) ? qarr : (blockIdx.y == 1) ? karr
                : (blockIdx.y == 2) ? varr : sarr;

    const __bf16* asrc[2];
    __bf16* aldst[2];
#pragma unroll
    for (int j = 0; j < 2; j++) {
        int u = j * 256 + t;
        int row = r0 + (u & 127);
        if (row >= NNODES) row = NNODES - 1;
        asrc[j] = hbf + (size_t)row * HMID + (u >> 7) * 8;
        aldst[j] = &As[(size_t)u * 8];
    }
    const __bf16* bsrc[2];
    __bf16* bldst[2];
#pragma unroll
    for (int j = 0; j < 2; j++) {
        int u = j * 256 + t;
        bsrc[j] = Wallt + (size_t)(c0 + (u & 127)) * HMID + (u >> 7) * 8;
        bldst[j] = &Bs[(size_t)u * 8];
    }

    f32x4 acc[4][4] = {};

    for (int k0 = 0; k0 < HMID; k0 += 32) {
#pragma unroll
        for (int j = 0; j < 2; j++) async_copy16(asrc[j] + k0, aldst[j]);
#pragma unroll
        for (int j = 0; j < 2; j++) async_copy16(bsrc[j] + k0, bldst[j]);
        __syncthreads();

        bf16x8 af[4], bfr[4];
#pragma unroll
        for (int i = 0; i < 4; i++) af[i] = *(const bf16x8*)&As[(size_t)(q * 128 + wr + i * 16 + m) * 8];
#pragma unroll
        for (int jb = 0; jb < 4; jb++) bfr[jb] = *(const bf16x8*)&Bs[(size_t)(q * 128 + wc + jb * 16 + m) * 8];
#pragma unroll
        for (int i = 0; i < 4; i++)
#pragma unroll
            for (int jb = 0; jb < 4; jb++)
                acc[i][jb] = __builtin_amdgcn_mfma_f32_16x16x32_bf16(af[i], bfr[jb], acc[i][jb], 0, 0, 0);
        __syncthreads();
    }

#pragma unroll
    for (int jb = 0; jb < 4; jb++) {
        int dcol = wc + jb * 16 + m;
        float bias = ball[c0 + dcol];
#pragma unroll
        for (int i = 0; i < 4; i++)
#pragma unroll
            for (int r = 0; r < 4; r++) {
                int row = r0 + wr + i * 16 + q * 4 + r;
                if (row < NNODES) tbl[(size_t)row * 128 + dcol] = (__bf16)(acc[i][jb][r] + bias);
            }
    }
}

// ---------------- attention scores: per-block partial sums ----------------
__global__ __launch_bounds__(256) void k_alpha(const int* __restrict__ rowptr,
                                               const int* __restrict__ srcsorted,
                                               const __bf16* __restrict__ qarr,
                                               const __bf16* __restrict__ karr,
                                               float* __restrict__ alpha,
                                               float* __restrict__ part) {
    int n = (blockIdx.x * 256 + threadIdx.x) >> 6;
    int lane = threadIdx.x & 63;
    int g = lane >> 4, l = lane & 15;
    float s1 = 0.f, s2 = 0.f;
    if (n < NNODES) {
        bf16x8 qb = *(const bf16x8*)(qarr + (size_t)n * 128 + l * 8);
        float qf[8];
#pragma unroll
        for (int j = 0; j < 8; j++) qf[j] = (float)qb[j];
        int beg = rowptr[n], end = rowptr[n + 1];
        for (int i = beg + g; i < end; i += 16) {
            int i1 = i + 4 < end ? i + 4 : end - 1;
            int i2 = i + 8 < end ? i + 8 : end - 1;
            int i3 = i + 12 < end ? i + 12 : end - 1;
            int s0 = srcsorted[i], sA = srcsorted[i1], sB = srcsorted[i2], sC = srcsorted[i3];
            bf16x8 k0 = *(const bf16x8*)(karr + (size_t)s0 * 128 + l * 8);
            bf16x8 k1 = *(const bf16x8*)(karr + (size_t)sA * 128 + l * 8);
            bf16x8 k2 = *(const bf16x8*)(karr + (size_t)sB * 128 + l * 8);
            bf16x8 k3 = *(const bf16x8*)(karr + (size_t)sC * 128 + l * 8);
            float d0 = 0.f, d1 = 0.f, d2 = 0.f, d3 = 0.f;
#pragma unroll
            for (int j = 0; j < 8; j++) {
                d0 += qf[j] * (float)k0[j];
                d1 += qf[j] * (float)k1[j];
                d2 += qf[j] * (float)k2[j];
                d3 += qf[j] * (float)k3[j];
            }
#pragma unroll
            for (int off = 1; off < 16; off <<= 1) {
                d0 += __shfl_xor(d0, off, 64);
                d1 += __shfl_xor(d1, off, 64);
                d2 += __shfl_xor(d2, off, 64);
                d3 += __shfl_xor(d3, off, 64);
            }
            if (l == 0) {
                const float sc = 0.08838834764831845f;  // 1/sqrt(128)
                float a0 = d0 * sc;
                alpha[i] = a0; s1 += a0; s2 += a0 * a0;
                if (i + 4 < end)  { float a = d1 * sc; alpha[i + 4]  = a; s1 += a; s2 += a * a; }
                if (i + 8 < end)  { float a = d2 * sc; alpha[i + 8]  = a; s1 += a; s2 += a * a; }
                if (i + 12 < end) { float a = d3 * sc; alpha[i + 12] = a; s1 += a; s2 += a * a; }
            }
        }
    }
#pragma unroll
    for (int off = 1; off < 64; off <<= 1) {
        s1 += __shfl_xor(s1, off, 64);
        s2 += __shfl_xor(s2, off, 64);
    }
    __shared__ float sh[8];
    int wave = threadIdx.x >> 6;
    if ((threadIdx.x & 63) == 0) { sh[wave] = s1; sh[4 + wave] = s2; }
    __syncthreads();
    if (threadIdx.x == 0) {
        part[2 * blockIdx.x]     = sh[0] + sh[1] + sh[2] + sh[3];
        part[2 * blockIdx.x + 1] = sh[4] + sh[5] + sh[6] + sh[7];
    }
}

__global__ __launch_bounds__(1024) void k_stats(const float* __restrict__ part,
                                                float* __restrict__ S) {
    float s1 = 0.f, s2 = 0.f;
    for (int i = threadIdx.x; i < ALPHA_BLOCKS; i += 1024) {
        s1 += part[2 * i];
        s2 += part[2 * i + 1];
    }
#pragma unroll
    for (int off = 1; off < 64; off <<= 1) {
        s1 += __shfl_xor(s1, off, 64);
        s2 += __shfl_xor(s2, off, 64);
    }
    __shared__ float sh1[16], sh2[16];
    int wave = threadIdx.x >> 6;
    if ((threadIdx.x & 63) == 0) { sh1[wave] = s1; sh2[wave] = s2; }
    __syncthreads();
    if (threadIdx.x == 0) {
        float t1 = 0.f, t2 = 0.f;
#pragma unroll
        for (int w = 0; w < 16; w++) { t1 += sh1[w]; t2 += sh2[w]; }
        float mean = t1 / (float)EEDGES;
        float var = (t2 - (float)EEDGES * mean * mean) / (float)(EEDGES - 1);
        float stdv = sqrtf(fmaxf(var, 1e-20f));
        S[2] = mean;
        S[3] = 3.0f / stdv;
    }
}

// ---------------- output gather (batch-4 MLP) ----------------
__global__ __launch_bounds__(256) void k_msg_gather(const int* __restrict__ rowptr,
                                                    const int* __restrict__ srcsorted,
                                                    const __bf16* __restrict__ varr,
                                                    const __bf16* __restrict__ sarr,
                                                    const float* __restrict__ alpha,
                                                    const float* __restrict__ S,
                                                    float* __restrict__ out) {
    int n = (blockIdx.x * 256 + threadIdx.x) >> 6;
    int l = threadIdx.x & 63;
    if (n >= NNODES) return;
    float mean = S[2], scl = S[3];
    bf16x2 sb = *(const bf16x2*)(sarr + (size_t)n * 128 + l * 2);
    float ax = (float)sb[0], ay = (float)sb[1];
    int beg = rowptr[n], end = rowptr[n + 1];
    for (int i = beg; i < end; i += 4) {
        int i1 = i + 1 < end ? i + 1 : end - 1;
        int i2 = i + 2 < end ? i + 2 : end - 1;
        int i3 = i + 3 < end ? i + 3 : end - 1;
        int s0 = srcsorted[i], s1 = srcsorted[i1], s2 = srcsorted[i2], s3 = srcsorted[i3];
        float z0 = (alpha[i] - mean) * scl;
        float z1 = (alpha[i1] - mean) * scl;
        float z2 = (alpha[i2] - mean) * scl;
        float z3 = (alpha[i3] - mean) * scl;
        float g0 = 1.0f / (1.0f + __expf(-z0));
        float g1 = (i + 1 < end) ? 1.0f / (1.0f + __expf(-z1)) : 0.f;
        float g2 = (i + 2 < end) ? 1.0f / (1.0f + __expf(-z2)) : 0.f;
        float g3 = (i + 3 < end) ? 1.0f / (1.0f + __expf(-z3)) : 0.f;
        bf16x2 v0 = *(const bf16x2*)(varr + (size_t)s0 * 128 + l * 2);
        bf16x2 v1 = *(const bf16x2*)(varr + (size_t)s1 * 128 + l * 2);
        bf16x2 v2 = *(const bf16x2*)(varr + (size_t)s2 * 128 + l * 2);
        bf16x2 v3 = *(const bf16x2*)(varr + (size_t)s3 * 128 + l * 2);
        ax += (float)v0[0] * g0 + (float)v1[0] * g1 + (float)v2[0] * g2 + (float)v3[0] * g3;
        ay += (float)v0[1] * g0 + (float)v1[1] * g1 + (float)v2[1] * g2 + (float)v3[1] * g3;
    }
    float2 o; o.x = ax; o.y = ay;
    ((float2*)(out + (size_t)n * DOUT))[l] = o;
}

// ---------------- launch ----------------
extern "C" void kernel_launch(void* const* d_in, const int* in_sizes, int n_in,
                              void* d_out, int out_size, void* d_ws, size_t ws_size,
                              hipStream_t stream) {
    const float* x  = (const float*)d_in[0];
    const int* ei   = (const int*)d_in[1];
    const int* srcI = ei;
    const int* dstI = ei + EEDGES;
    const float* Wg = (const float*)d_in[2];
    const float* bg = (const float*)d_in[3];
    const float* Wq = (const float*)d_in[4];  const float* bq = (const float*)d_in[5];
    const float* Wk = (const float*)d_in[6];  const float* bk = (const float*)d_in[7];
    const float* Wv = (const float*)d_in[8];  const float* bv = (const float*)d_in[9];
    const float* Ws = (const float*)d_in[10]; const float* bs = (const float*)d_in[11];
    float* out = (float*)d_out;

    char* wsb = (char*)d_ws;
    size_t off = 0;
    auto alloc = [&](size_t bytes) -> void* {
        void* p = wsb + off;
        off += (bytes + 255) & ~(size_t)255;
        return p;
    };
    int*    cnt    = (int*)alloc((size_t)NNODES * 4);
    int*    rowptr = (int*)alloc((size_t)(NNODES + 1) * 4);
    int*    cursor = (int*)alloc((size_t)NNODES * 4);
    int*    srcst  = (int*)alloc((size_t)EEDGES * 4);
    float*  wsort  = (float*)alloc((size_t)EEDGES * 4);
    float*  dinv   = (float*)alloc((size_t)NNODES * 4);
    float*  S      = (float*)alloc(64);
    float*  part   = (float*)alloc((size_t)ALPHA_BLOCKS * 2 * 4);
    __bf16* Wt     = (__bf16*)alloc((size_t)HMID * FIN * 2);
    __bf16* Wallt  = (__bf16*)alloc((size_t)512 * HMID * 2);
    float*  ball   = (float*)alloc(512 * 4);
    __bf16* h0bf   = (__bf16*)alloc((size_t)NNODES * HMID * 2);
    __bf16* hbf    = (__bf16*)alloc((size_t)NNODES * HMID * 2);
    __bf16* qarr   = (__bf16*)alloc((size_t)NNODES * 128 * 2);
    __bf16* karr   = (__bf16*)alloc((size_t)NNODES * 128 * 2);
    __bf16* varr   = (__bf16*)alloc((size_t)NNODES * 128 * 2);
    __bf16* sarr   = (__bf16*)alloc((size_t)NNODES * 128 * 2);
    float*  alphab = (float*)alloc((size_t)EEDGES * 4);
    if (off > ws_size) return;

    k_prep_wgcn<<<(FIN * HMID + 255) / 256, 256, 0, stream>>>(Wg, Wt);
    dim3 gw((HMID * DOUT + 255) / 256, 4);
    k_prep_watt<<<gw, 256, 0, stream>>>(Wq, Wk, Wv, Ws, bq, bk, bv, bs, Wallt, ball);

    k_init<<<(NNODES + 255) / 256, 256, 0, stream>>>(cnt, S);
    k_count<<<(EEDGES + 255) / 256, 256, 0, stream>>>(dstI, cnt);
    k_dinv<<<(NNODES + 255) / 256, 256, 0, stream>>>(cnt, dinv, cursor);
    k_scan<<<1, 1024, 0, stream>>>(cnt, rowptr);
    k_fill<<<(EEDGES + 255) / 256, 256, 0, stream>>>(srcI, dstI, rowptr, cursor, dinv, srcst, wsort);

    k_gemm1<<<(NNODES + 63) / 64, 256, 0, stream>>>(x, Wt, h0bf);

    k_gcn_gather<<<(NNODES * 64 + 255) / 256, 256, 0, stream>>>(rowptr, srcst, wsort, h0bf, dinv, bg, hbf);

    dim3 g2((NNODES + 127) / 128, 4);
    k_gemm2<<<g2, 256, 0, stream>>>(hbf, Wallt, ball, qarr, karr, varr, sarr);

    k_alpha<<<ALPHA_BLOCKS, 256, 0, stream>>>(rowptr, srcst, qarr, karr, alphab, part);
    k_stats<<<1, 1024, 0, stream>>>(part, S);

    k_msg_gather<<<(NNODES * 64 + 255) / 256, 256, 0, stream>>>(rowptr, srcst, varr, sarr, alphab, S, out);
}

// Round 7
// 342.132 us; speedup vs baseline: 1.0344x; 1.0344x over previous
//
#include <hip/hip_runtime.h>
#include <hip/hip_bf16.h>

#define NNODES 20000
#define EEDGES 320000
#define FIN 1024
#define HMID 256
#define DOUT 128
#define ALPHA_BLOCKS ((NNODES + 3) / 4)

typedef __bf16 bf16x8 __attribute__((ext_vector_type(8)));
typedef __bf16 bf16x4 __attribute__((ext_vector_type(4)));
typedef __bf16 bf16x2 __attribute__((ext_vector_type(2)));
typedef float f32x4 __attribute__((ext_vector_type(4)));

typedef const __attribute__((address_space(1))) void* gas_ptr;
typedef __attribute__((address_space(3))) void* las_ptr;
__device__ __forceinline__ void async_copy16(const void* g, void* l) {
    __builtin_amdgcn_global_load_lds((gas_ptr)g, (las_ptr)l, 16, 0, 0);
}

// ---------------- weight prep ----------------
__global__ void k_prep_wgcn(const float* __restrict__ W, __bf16* __restrict__ Wt) {
    int tid = blockIdx.x * 256 + threadIdx.x;
    if (tid >= FIN * HMID) return;
    int k = tid >> 8;
    int n = tid & 255;
    Wt[(size_t)n * FIN + k] = (__bf16)W[tid];
}

__global__ void k_prep_watt(const float* __restrict__ Wq, const float* __restrict__ Wk,
                            const float* __restrict__ Wv, const float* __restrict__ Ws,
                            const float* __restrict__ bq, const float* __restrict__ bk,
                            const float* __restrict__ bv, const float* __restrict__ bs,
                            __bf16* __restrict__ Wallt, float* __restrict__ ball) {
    int g = blockIdx.y;
    const float* W = (g == 0) ? Wq : (g == 1) ? Wk : (g == 2) ? Wv : Ws;
    int tid = blockIdx.x * 256 + threadIdx.x;
    if (tid < HMID * DOUT) {
        int k = tid >> 7;
        int n = tid & 127;
        Wallt[(size_t)(g * DOUT + n) * HMID + k] = (__bf16)W[tid];
    }
    if (tid < DOUT) {
        const float* b = (g == 0) ? bq : (g == 1) ? bk : (g == 2) ? bv : bs;
        ball[g * DOUT + tid] = b[tid];
    }
}

// ---------------- CSR build ----------------
__global__ void k_init(int* __restrict__ cnt, float* __restrict__ S) {
    int i = blockIdx.x * 256 + threadIdx.x;
    if (i < NNODES) cnt[i] = 0;
    if (i < 16) S[i] = 0.0f;
}

__global__ void k_count(const int* __restrict__ dst, int* __restrict__ cnt) {
    int e = blockIdx.x * 256 + threadIdx.x;
    if (e < EEDGES) atomicAdd(&cnt[dst[e]], 1);
}

__global__ void k_dinv(const int* __restrict__ cnt, float* __restrict__ dinv,
                       int* __restrict__ cursor) {
    int i = blockIdx.x * 256 + threadIdx.x;
    if (i < NNODES) {
        dinv[i] = rsqrtf((float)cnt[i] + 1.0f);
        cursor[i] = 0;
    }
}

__global__ __launch_bounds__(1024) void k_scan(const int* __restrict__ cnt,
                                               int* __restrict__ rowptr) {
    __shared__ int sh[1024];
    int t = threadIdx.x;
    int base = t * 20;
    int local[20];
    int sum = 0;
#pragma unroll
    for (int j = 0; j < 20; j++) {
        int i = base + j;
        int v = (i < NNODES) ? cnt[i] : 0;
        local[j] = sum;
        sum += v;
    }
    sh[t] = sum;
    __syncthreads();
    for (int off = 1; off < 1024; off <<= 1) {
        int v = (t >= off) ? sh[t - off] : 0;
        __syncthreads();
        sh[t] += v;
        __syncthreads();
    }
    int prev = (t > 0) ? sh[t - 1] : 0;
#pragma unroll
    for (int j = 0; j < 20; j++) {
        int i = base + j;
        if (i < NNODES) rowptr[i] = prev + local[j];
    }
    if (t == 1023) rowptr[NNODES] = sh[1023];
}

__global__ void k_fill(const int* __restrict__ src, const int* __restrict__ dst,
                       const int* __restrict__ rowptr, int* __restrict__ cursor,
                       const float* __restrict__ dinv,
                       int* __restrict__ srcsorted, float* __restrict__ wsorted) {
    int e = blockIdx.x * 256 + threadIdx.x;
    if (e >= EEDGES) return;
    int d = dst[e];
    int s = src[e];
    int pos = atomicAdd(&cursor[d], 1);
    int w = rowptr[d] + pos;
    srcsorted[w] = s;
    wsorted[w] = dinv[s];
}

// ---------------- GEMM1: h0bf = bf16(x @ W_gcn) ----------------
// TLP-first: 512 threads (8 waves), 64x128 tile, grid (313, 2) = 626 blocks
// -> ~19 waves/CU so bulk-synchronous stalls of different blocks overlap.
// As: [8 kchunk][64 row] x 4 fp32 (8 KB).  Bs: [4 kchunk][128 col] x 8 bf16 (8 KB).
// Exactly 1 A-load + 1 B-load (16 B) per thread per K-step.
__global__ __launch_bounds__(512) void k_gemm1(const float* __restrict__ x,
                                               const __bf16* __restrict__ Wt,
                                               __bf16* __restrict__ h0bf) {
    __shared__ float As[2048];     // 8 KB
    __shared__ __bf16 Bs[4096];    // 8 KB
    int t = threadIdx.x;
    int lane = t & 63;
    int m = lane & 15, q = lane >> 4;
    int wave = t >> 6;             // 0..7
    int wr = (wave & 1) * 32;
    int wc = (wave >> 1) * 32;
    int r0 = blockIdx.x * 64;
    int c0 = blockIdx.y * 128;

    // A staging: unit t: row = t&63, kc = t>>6 (0..7, 4 floats)
    int arow = r0 + (t & 63);
    if (arow >= NNODES) arow = NNODES - 1;
    const float* asrc = x + (size_t)arow * FIN + (t >> 6) * 4;
    float* aldst = &As[t * 4];
    // B staging: unit t: col = t&127, kc = t>>7 (0..3, 8 bf16)
    const __bf16* bsrc = Wt + (size_t)(c0 + (t & 127)) * FIN + (t >> 7) * 8;
    __bf16* bldst = &Bs[t * 8];

    f32x4 acc[2][2] = {};

    for (int k0 = 0; k0 < FIN; k0 += 32) {
        async_copy16(asrc + k0, aldst);
        async_copy16(bsrc + k0, bldst);
        __syncthreads();

        bf16x8 af[2], bfr[2];
#pragma unroll
        for (int i = 0; i < 2; i++) {
            int R = wr + i * 16 + m;
            f32x4 a0 = *(const f32x4*)&As[((2 * q) * 64 + R) * 4];
            f32x4 a1 = *(const f32x4*)&As[((2 * q + 1) * 64 + R) * 4];
            bf16x8 a;
            a[0] = (__bf16)a0[0]; a[1] = (__bf16)a0[1]; a[2] = (__bf16)a0[2]; a[3] = (__bf16)a0[3];
            a[4] = (__bf16)a1[0]; a[5] = (__bf16)a1[1]; a[6] = (__bf16)a1[2]; a[7] = (__bf16)a1[3];
            af[i] = a;
        }
#pragma unroll
        for (int jb = 0; jb < 2; jb++) {
            int C = wc + jb * 16 + m;
            bfr[jb] = *(const bf16x8*)&Bs[(q * 128 + C) * 8];
        }
#pragma unroll
        for (int i = 0; i < 2; i++)
#pragma unroll
            for (int jb = 0; jb < 2; jb++)
                acc[i][jb] = __builtin_amdgcn_mfma_f32_16x16x32_bf16(af[i], bfr[jb], acc[i][jb], 0, 0, 0);
        __syncthreads();
    }

#pragma unroll
    for (int i = 0; i < 2; i++)
#pragma unroll
        for (int jb = 0; jb < 2; jb++)
#pragma unroll
            for (int r = 0; r < 4; r++) {
                int row = r0 + wr + i * 16 + q * 4 + r;
                int col = c0 + wc + jb * 16 + m;
                if (row < NNODES) h0bf[(size_t)row * 256 + col] = (__bf16)acc[i][jb][r];
            }
}

// ---------------- GCN gather (batch-4 MLP) ----------------
__global__ __launch_bounds__(256) void k_gcn_gather(const int* __restrict__ rowptr,
                                                    const int* __restrict__ srcsorted,
                                                    const float* __restrict__ wsorted,
                                                    const __bf16* __restrict__ h0bf,
                                                    const float* __restrict__ dinv,
                                                    const float* __restrict__ bgcn,
                                                    __bf16* __restrict__ hbf) {
    int gid = blockIdx.x * 256 + threadIdx.x;
    int n = gid >> 6, l = gid & 63;
    if (n >= NNODES) return;
    float dn = dinv[n];
    float wn = dn * dn;
    bf16x4 hv = *(const bf16x4*)(h0bf + (size_t)n * 256 + l * 4);
    float4 b = ((const float4*)bgcn)[l];
    float ax = (float)hv[0] * wn + b.x;
    float ay = (float)hv[1] * wn + b.y;
    float az = (float)hv[2] * wn + b.z;
    float aw = (float)hv[3] * wn + b.w;
    int beg = rowptr[n], end = rowptr[n + 1];
    for (int i = beg; i < end; i += 4) {
        int i1 = i + 1 < end ? i + 1 : end - 1;
        int i2 = i + 2 < end ? i + 2 : end - 1;
        int i3 = i + 3 < end ? i + 3 : end - 1;
        int s0 = srcsorted[i], s1 = srcsorted[i1], s2 = srcsorted[i2], s3 = srcsorted[i3];
        float w0 = wsorted[i] * dn;
        float w1 = (i + 1 < end) ? wsorted[i1] * dn : 0.f;
        float w2 = (i + 2 < end) ? wsorted[i2] * dn : 0.f;
        float w3 = (i + 3 < end) ? wsorted[i3] * dn : 0.f;
        bf16x4 v0 = *(const bf16x4*)(h0bf + (size_t)s0 * 256 + l * 4);
        bf16x4 v1 = *(const bf16x4*)(h0bf + (size_t)s1 * 256 + l * 4);
        bf16x4 v2 = *(const bf16x4*)(h0bf + (size_t)s2 * 256 + l * 4);
        bf16x4 v3 = *(const bf16x4*)(h0bf + (size_t)s3 * 256 + l * 4);
        ax += (float)v0[0] * w0 + (float)v1[0] * w1 + (float)v2[0] * w2 + (float)v3[0] * w3;
        ay += (float)v0[1] * w0 + (float)v1[1] * w1 + (float)v2[1] * w2 + (float)v3[1] * w3;
        az += (float)v0[2] * w0 + (float)v1[2] * w1 + (float)v2[2] * w2 + (float)v3[2] * w3;
        aw += (float)v0[3] * w0 + (float)v1[3] * w1 + (float)v2[3] * w2 + (float)v3[3] * w3;
    }
    bf16x4 o;
    o[0] = (__bf16)(ax >= 0.f ? ax : 0.01f * ax);
    o[1] = (__bf16)(ay >= 0.f ? ay : 0.01f * ay);
    o[2] = (__bf16)(az >= 0.f ? az : 0.01f * az);
    o[3] = (__bf16)(aw >= 0.f ? aw : 0.01f * aw);
    *(bf16x4*)(hbf + (size_t)n * 256 + l * 4) = o;
}

// ---------------- GEMM2: q/k/v/s tables = hbf @ Wallt + ball ----------------
__global__ __launch_bounds__(256) void k_gemm2(const __bf16* __restrict__ hbf,
                                               const __bf16* __restrict__ Wallt,
                                               const float* __restrict__ ball,
                                               __bf16* __restrict__ qarr,
                                               __bf16* __restrict__ karr,
                                               __bf16* __restrict__ varr,
                                               __bf16* __restrict__ sarr) {
    __shared__ __bf16 As[4096];
    __shared__ __bf16 Bs[4096];
    int t = threadIdx.x;
    int lane = t & 63;
    int m = lane & 15, q = lane >> 4;
    int wave = t >> 6;
    int wr = (wave & 1) * 64;
    int wc = (wave >> 1) * 64;
    int r0 = blockIdx.x * 128;
    int c0 = blockIdx.y * 128;
    __bf16* tbl = (blockIdx.y == 0) ? qarr : (blockIdx.y == 1) ? karr
                : (blockIdx.y == 2) ? varr : sarr;

    const __bf16* asrc[2];
    __bf16* aldst[2];
#pragma unroll
    for (int j = 0; j < 2; j++) {
        int u = j * 256 + t;
        int row = r0 + (u & 127);
        if (row >= NNODES) row = NNODES - 1;
        asrc[j] = hbf + (size_t)row * HMID + (u >> 7) * 8;
        aldst[j] = &As[(size_t)u * 8];
    }
    const __bf16* bsrc[2];
    __bf16* bldst[2];
#pragma unroll
    for (int j = 0; j < 2; j++) {
        int u = j * 256 + t;
        bsrc[j] = Wallt + (size_t)(c0 + (u & 127)) * HMID + (u >> 7) * 8;
        bldst[j] = &Bs[(size_t)u * 8];
    }

    f32x4 acc[4][4] = {};

    for (int k0 = 0; k0 < HMID; k0 += 32) {
#pragma unroll
        for (int j = 0; j < 2; j++) async_copy16(asrc[j] + k0, aldst[j]);
#pragma unroll
        for (int j = 0; j < 2; j++) async_copy16(bsrc[j] + k0, bldst[j]);
        __syncthreads();

        bf16x8 af[4], bfr[4];
#pragma unroll
        for (int i = 0; i < 4; i++) af[i] = *(const bf16x8*)&As[(size_t)(q * 128 + wr + i * 16 + m) * 8];
#pragma unroll
        for (int jb = 0; jb < 4; jb++) bfr[jb] = *(const bf16x8*)&Bs[(size_t)(q * 128 + wc + jb * 16 + m) * 8];
#pragma unroll
        for (int i = 0; i < 4; i++)
#pragma unroll
            for (int jb = 0; jb < 4; jb++)
                acc[i][jb] = __builtin_amdgcn_mfma_f32_16x16x32_bf16(af[i], bfr[jb], acc[i][jb], 0, 0, 0);
        __syncthreads();
    }

#pragma unroll
    for (int jb = 0; jb < 4; jb++) {
        int dcol = wc + jb * 16 + m;
        float bias = ball[c0 + dcol];
#pragma unroll
        for (int i = 0; i < 4; i++)
#pragma unroll
            for (int r = 0; r < 4; r++) {
                int row = r0 + wr + i * 16 + q * 4 + r;
                if (row < NNODES) tbl[(size_t)row * 128 + dcol] = (__bf16)(acc[i][jb][r] + bias);
            }
    }
}

// ---------------- attention scores: per-block partial sums ----------------
__global__ __launch_bounds__(256) void k_alpha(const int* __restrict__ rowptr,
                                               const int* __restrict__ srcsorted,
                                               const __bf16* __restrict__ qarr,
                                               const __bf16* __restrict__ karr,
                                               float* __restrict__ alpha,
                                               float* __restrict__ part) {
    int n = (blockIdx.x * 256 + threadIdx.x) >> 6;
    int lane = threadIdx.x & 63;
    int g = lane >> 4, l = lane & 15;
    float s1 = 0.f, s2 = 0.f;
    if (n < NNODES) {
        bf16x8 qb = *(const bf16x8*)(qarr + (size_t)n * 128 + l * 8);
        float qf[8];
#pragma unroll
        for (int j = 0; j < 8; j++) qf[j] = (float)qb[j];
        int beg = rowptr[n], end = rowptr[n + 1];
        for (int i = beg + g; i < end; i += 16) {
            int i1 = i + 4 < end ? i + 4 : end - 1;
            int i2 = i + 8 < end ? i + 8 : end - 1;
            int i3 = i + 12 < end ? i + 12 : end - 1;
            int s0 = srcsorted[i], sA = srcsorted[i1], sB = srcsorted[i2], sC = srcsorted[i3];
            bf16x8 k0 = *(const bf16x8*)(karr + (size_t)s0 * 128 + l * 8);
            bf16x8 k1 = *(const bf16x8*)(karr + (size_t)sA * 128 + l * 8);
            bf16x8 k2 = *(const bf16x8*)(karr + (size_t)sB * 128 + l * 8);
            bf16x8 k3 = *(const bf16x8*)(karr + (size_t)sC * 128 + l * 8);
            float d0 = 0.f, d1 = 0.f, d2 = 0.f, d3 = 0.f;
#pragma unroll
            for (int j = 0; j < 8; j++) {
                d0 += qf[j] * (float)k0[j];
                d1 += qf[j] * (float)k1[j];
                d2 += qf[j] * (float)k2[j];
                d3 += qf[j] * (float)k3[j];
            }
#pragma unroll
            for (int off = 1; off < 16; off <<= 1) {
                d0 += __shfl_xor(d0, off, 64);
                d1 += __shfl_xor(d1, off, 64);
                d2 += __shfl_xor(d2, off, 64);
                d3 += __shfl_xor(d3, off, 64);
            }
            if (l == 0) {
                const float sc = 0.08838834764831845f;  // 1/sqrt(128)
                float a0 = d0 * sc;
                alpha[i] = a0; s1 += a0; s2 += a0 * a0;
                if (i + 4 < end)  { float a = d1 * sc; alpha[i + 4]  = a; s1 += a; s2 += a * a; }
                if (i + 8 < end)  { float a = d2 * sc; alpha[i + 8]  = a; s1 += a; s2 += a * a; }
                if (i + 12 < end) { float a = d3 * sc; alpha[i + 12] = a; s1 += a; s2 += a * a; }
            }
        }
    }
#pragma unroll
    for (int off = 1; off < 64; off <<= 1) {
        s1 += __shfl_xor(s1, off, 64);
        s2 += __shfl_xor(s2, off, 64);
    }
    __shared__ float sh[8];
    int wave = threadIdx.x >> 6;
    if ((threadIdx.x & 63) == 0) { sh[wave] = s1; sh[4 + wave] = s2; }
    __syncthreads();
    if (threadIdx.x == 0) {
        part[2 * blockIdx.x]     = sh[0] + sh[1] + sh[2] + sh[3];
        part[2 * blockIdx.x + 1] = sh[4] + sh[5] + sh[6] + sh[7];
    }
}

__global__ __launch_bounds__(1024) void k_stats(const float* __restrict__ part,
                                                float* __restrict__ S) {
    float s1 = 0.f, s2 = 0.f;
    for (int i = threadIdx.x; i < ALPHA_BLOCKS; i += 1024) {
        s1 += part[2 * i];
        s2 += part[2 * i + 1];
    }
#pragma unroll
    for (int off = 1; off < 64; off <<= 1) {
        s1 += __shfl_xor(s1, off, 64);
        s2 += __shfl_xor(s2, off, 64);
    }
    __shared__ float sh1[16], sh2[16];
    int wave = threadIdx.x >> 6;
    if ((threadIdx.x & 63) == 0) { sh1[wave] = s1; sh2[wave] = s2; }
    __syncthreads();
    if (threadIdx.x == 0) {
        float t1 = 0.f, t2 = 0.f;
#pragma unroll
        for (int w = 0; w < 16; w++) { t1 += sh1[w]; t2 += sh2[w]; }
        float mean = t1 / (float)EEDGES;
        float var = (t2 - (float)EEDGES * mean * mean) / (float)(EEDGES - 1);
        float stdv = sqrtf(fmaxf(var, 1e-20f));
        S[2] = mean;
        S[3] = 3.0f / stdv;
    }
}

// ---------------- output gather (batch-4 MLP) ----------------
__global__ __launch_bounds__(256) void k_msg_gather(const int* __restrict__ rowptr,
                                                    const int* __restrict__ srcsorted,
                                                    const __bf16* __restrict__ varr,
                                                    const __bf16* __restrict__ sarr,
                                                    const float* __restrict__ alpha,
                                                    const float* __restrict__ S,
                                                    float* __restrict__ out) {
    int n = (blockIdx.x * 256 + threadIdx.x) >> 6;
    int l = threadIdx.x & 63;
    if (n >= NNODES) return;
    float mean = S[2], scl = S[3];
    bf16x2 sb = *(const bf16x2*)(sarr + (size_t)n * 128 + l * 2);
    float ax = (float)sb[0], ay = (float)sb[1];
    int beg = rowptr[n], end = rowptr[n + 1];
    for (int i = beg; i < end; i += 4) {
        int i1 = i + 1 < end ? i + 1 : end - 1;
        int i2 = i + 2 < end ? i + 2 : end - 1;
        int i3 = i + 3 < end ? i + 3 : end - 1;
        int s0 = srcsorted[i], s1 = srcsorted[i1], s2 = srcsorted[i2], s3 = srcsorted[i3];
        float z0 = (alpha[i] - mean) * scl;
        float z1 = (alpha[i1] - mean) * scl;
        float z2 = (alpha[i2] - mean) * scl;
        float z3 = (alpha[i3] - mean) * scl;
        float g0 = 1.0f / (1.0f + __expf(-z0));
        float g1 = (i + 1 < end) ? 1.0f / (1.0f + __expf(-z1)) : 0.f;
        float g2 = (i + 2 < end) ? 1.0f / (1.0f + __expf(-z2)) : 0.f;
        float g3 = (i + 3 < end) ? 1.0f / (1.0f + __expf(-z3)) : 0.f;
        bf16x2 v0 = *(const bf16x2*)(varr + (size_t)s0 * 128 + l * 2);
        bf16x2 v1 = *(const bf16x2*)(varr + (size_t)s1 * 128 + l * 2);
        bf16x2 v2 = *(const bf16x2*)(varr + (size_t)s2 * 128 + l * 2);
        bf16x2 v3 = *(const bf16x2*)(varr + (size_t)s3 * 128 + l * 2);
        ax += (float)v0[0] * g0 + (float)v1[0] * g1 + (float)v2[0] * g2 + (float)v3[0] * g3;
        ay += (float)v0[1] * g0 + (float)v1[1] * g1 + (float)v2[1] * g2 + (float)v3[1] * g3;
    }
    float2 o; o.x = ax; o.y = ay;
    ((float2*)(out + (size_t)n * DOUT))[l] = o;
}

// ---------------- launch ----------------
extern "C" void kernel_launch(void* const* d_in, const int* in_sizes, int n_in,
                              void* d_out, int out_size, void* d_ws, size_t ws_size,
                              hipStream_t stream) {
    const float* x  = (const float*)d_in[0];
    const int* ei   = (const int*)d_in[1];
    const int* srcI = ei;
    const int* dstI = ei + EEDGES;
    const float* Wg = (const float*)d_in[2];
    const float* bg = (const float*)d_in[3];
    const float* Wq = (const float*)d_in[4];  const float* bq = (const float*)d_in[5];
    const float* Wk = (const float*)d_in[6];  const float* bk = (const float*)d_in[7];
    const float* Wv = (const float*)d_in[8];  const float* bv = (const float*)d_in[9];
    const float* Ws = (const float*)d_in[10]; const float* bs = (const float*)d_in[11];
    float* out = (float*)d_out;

    char* wsb = (char*)d_ws;
    size_t off = 0;
    auto alloc = [&](size_t bytes) -> void* {
        void* p = wsb + off;
        off += (bytes + 255) & ~(size_t)255;
        return p;
    };
    int*    cnt    = (int*)alloc((size_t)NNODES * 4);
    int*    rowptr = (int*)alloc((size_t)(NNODES + 1) * 4);
    int*    cursor = (int*)alloc((size_t)NNODES * 4);
    int*    srcst  = (int*)alloc((size_t)EEDGES * 4);
    float*  wsort  = (float*)alloc((size_t)EEDGES * 4);
    float*  dinv   = (float*)alloc((size_t)NNODES * 4);
    float*  S      = (float*)alloc(64);
    float*  part   = (float*)alloc((size_t)ALPHA_BLOCKS * 2 * 4);
    __bf16* Wt     = (__bf16*)alloc((size_t)HMID * FIN * 2);
    __bf16* Wallt  = (__bf16*)alloc((size_t)512 * HMID * 2);
    float*  ball   = (float*)alloc(512 * 4);
    __bf16* h0bf   = (__bf16*)alloc((size_t)NNODES * HMID * 2);
    __bf16* hbf    = (__bf16*)alloc((size_t)NNODES * HMID * 2);
    __bf16* qarr   = (__bf16*)alloc((size_t)NNODES * 128 * 2);
    __bf16* karr   = (__bf16*)alloc((size_t)NNODES * 128 * 2);
    __bf16* varr   = (__bf16*)alloc((size_t)NNODES * 128 * 2);
    __bf16* sarr   = (__bf16*)alloc((size_t)NNODES * 128 * 2);
    float*  alphab = (float*)alloc((size_t)EEDGES * 4);
    if (off > ws_size) return;

    k_prep_wgcn<<<(FIN * HMID + 255) / 256, 256, 0, stream>>>(Wg, Wt);
    dim3 gw((HMID * DOUT + 255) / 256, 4);
    k_prep_watt<<<gw, 256, 0, stream>>>(Wq, Wk, Wv, Ws, bq, bk, bv, bs, Wallt, ball);

    k_init<<<(NNODES + 255) / 256, 256, 0, stream>>>(cnt, S);
    k_count<<<(EEDGES + 255) / 256, 256, 0, stream>>>(dstI, cnt);
    k_dinv<<<(NNODES + 255) / 256, 256, 0, stream>>>(cnt, dinv, cursor);
    k_scan<<<1, 1024, 0, stream>>>(cnt, rowptr);
    k_fill<<<(EEDGES + 255) / 256, 256, 0, stream>>>(srcI, dstI, rowptr, cursor, dinv, srcst, wsort);

    dim3 g1((NNODES + 63) / 64, HMID / 128);
    k_gemm1<<<g1, 512, 0, stream>>>(x, Wt, h0bf);

    k_gcn_gather<<<(NNODES * 64 + 255) / 256, 256, 0, stream>>>(rowptr, srcst, wsort, h0bf, dinv, bg, hbf);

    dim3 g2((NNODES + 127) / 128, 4);
    k_gemm2<<<g2, 256, 0, stream>>>(hbf, Wallt, ball, qarr, karr, varr, sarr);

    k_alpha<<<ALPHA_BLOCKS, 256, 0, stream>>>(rowptr, srcst, qarr, karr, alphab, part);
    k_stats<<<1, 1024, 0, stream>>>(part, S);

    k_msg_gather<<<(NNODES * 64 + 255) / 256, 256, 0, stream>>>(rowptr, srcst, varr, sarr, alphab, S, out);
}

// Round 8
// 340.031 us; speedup vs baseline: 1.0408x; 1.0062x over previous
//
#include <hip/hip_runtime.h>
#include <hip/hip_bf16.h>

#define NNODES 20000
#define EEDGES 320000
#define FIN 1024
#define HMID 256
#define DOUT 128
#define ALPHA_BLOCKS ((NNODES + 3) / 4)
#define RTILES 313
#define XPACK_ELEMS ((size_t)RTILES * 65536)

typedef __bf16 bf16x8 __attribute__((ext_vector_type(8)));
typedef __bf16 bf16x4 __attribute__((ext_vector_type(4)));
typedef __bf16 bf16x2 __attribute__((ext_vector_type(2)));
typedef float f32x4 __attribute__((ext_vector_type(4)));

typedef const __attribute__((address_space(1))) void* gas_ptr;
typedef __attribute__((address_space(3))) void* las_ptr;
__device__ __forceinline__ void async_copy16(const void* g, void* l) {
    __builtin_amdgcn_global_load_lds((gas_ptr)g, (las_ptr)l, 16, 0, 0);
}

// ---------------- operand packing ----------------
__global__ __launch_bounds__(256) void k_pack_x(const float* __restrict__ x,
                                                __bf16* __restrict__ xpack) {
    int slot = (blockIdx.x * 256 + threadIdx.x) >> 6;
    int l = threadIdx.x & 63;
    int R = slot >> 6, r = slot & 63;
    int row = slot < NNODES ? slot : NNODES - 1;
    const float4* xr = (const float4*)(x + (size_t)row * FIN);
    size_t base = (size_t)R * 65536;
#pragma unroll
    for (int c = 0; c < 2; c++) {
        float4 a0 = xr[c * 128 + l * 2];
        float4 a1 = xr[c * 128 + l * 2 + 1];
        bf16x8 o;
        o[0] = (__bf16)a0.x; o[1] = (__bf16)a0.y; o[2] = (__bf16)a0.z; o[3] = (__bf16)a0.w;
        o[4] = (__bf16)a1.x; o[5] = (__bf16)a1.y; o[6] = (__bf16)a1.z; o[7] = (__bf16)a1.w;
        int kk = c * 16 + (l >> 2);
        int u = (l & 3) * 64 + r;
        *(bf16x8*)(xpack + base + ((size_t)kk * 256 + u) * 8) = o;
    }
}

__global__ void k_pack_w(const float* __restrict__ W, __bf16* __restrict__ Wtp) {
    int tid = blockIdx.x * 256 + threadIdx.x;
    if (tid >= FIN * HMID) return;
    int k = tid >> 8;
    int n = tid & 255;
    int kk = k >> 5, kq = (k >> 3) & 3, j = k & 7;
    int h = n >> 7;
    int u = kq * 128 + (n & 127);
    Wtp[((size_t)(kk * 2 + h) * 512 + u) * 8 + j] = (__bf16)W[tid];
}

__global__ void k_prep_watt(const float* __restrict__ Wq, const float* __restrict__ Wk,
                            const float* __restrict__ Wv, const float* __restrict__ Ws,
                            const float* __restrict__ bq, const float* __restrict__ bk,
                            const float* __restrict__ bv, const float* __restrict__ bs,
                            __bf16* __restrict__ Wallt, float* __restrict__ ball) {
    int g = blockIdx.y;
    const float* W = (g == 0) ? Wq : (g == 1) ? Wk : (g == 2) ? Wv : Ws;
    int tid = blockIdx.x * 256 + threadIdx.x;
    if (tid < HMID * DOUT) {
        int k = tid >> 7;
        int n = tid & 127;
        Wallt[(size_t)(g * DOUT + n) * HMID + k] = (__bf16)W[tid];
    }
    if (tid < DOUT) {
        const float* b = (g == 0) ? bq : (g == 1) ? bk : (g == 2) ? bv : bs;
        ball[g * DOUT + tid] = b[tid];
    }
}

// ---------------- CSR build ----------------
__global__ void k_init(int* __restrict__ cnt, float* __restrict__ S) {
    int i = blockIdx.x * 256 + threadIdx.x;
    if (i < NNODES) cnt[i] = 0;
    if (i < 16) S[i] = 0.0f;
}

__global__ void k_count(const int* __restrict__ dst, int* __restrict__ cnt) {
    int e = blockIdx.x * 256 + threadIdx.x;
    if (e < EEDGES) atomicAdd(&cnt[dst[e]], 1);
}

__global__ void k_dinv(const int* __restrict__ cnt, float* __restrict__ dinv,
                       int* __restrict__ cursor) {
    int i = blockIdx.x * 256 + threadIdx.x;
    if (i < NNODES) {
        dinv[i] = rsqrtf((float)cnt[i] + 1.0f);
        cursor[i] = 0;
    }
}

__global__ __launch_bounds__(1024) void k_scan(const int* __restrict__ cnt,
                                               int* __restrict__ rowptr) {
    __shared__ int sh[1024];
    int t = threadIdx.x;
    int base = t * 20;
    int local[20];
    int sum = 0;
#pragma unroll
    for (int j = 0; j < 20; j++) {
        int i = base + j;
        int v = (i < NNODES) ? cnt[i] : 0;
        local[j] = sum;
        sum += v;
    }
    sh[t] = sum;
    __syncthreads();
    for (int off = 1; off < 1024; off <<= 1) {
        int v = (t >= off) ? sh[t - off] : 0;
        __syncthreads();
        sh[t] += v;
        __syncthreads();
    }
    int prev = (t > 0) ? sh[t - 1] : 0;
#pragma unroll
    for (int j = 0; j < 20; j++) {
        int i = base + j;
        if (i < NNODES) rowptr[i] = prev + local[j];
    }
    if (t == 1023) rowptr[NNODES] = sh[1023];
}

__global__ void k_fill(const int* __restrict__ src, const int* __restrict__ dst,
                       const int* __restrict__ rowptr, int* __restrict__ cursor,
                       const float* __restrict__ dinv,
                       int* __restrict__ srcsorted, float* __restrict__ wsorted) {
    int e = blockIdx.x * 256 + threadIdx.x;
    if (e >= EEDGES) return;
    int d = dst[e];
    int s = src[e];
    int pos = atomicAdd(&cursor[d], 1);
    int w = rowptr[d] + pos;
    srcsorted[w] = s;
    wsorted[w] = dinv[s];
}

// ---------------- GEMM1: packed operands, wave-contiguous staging ----------------
__global__ __launch_bounds__(256) void k_gemm1(const __bf16* __restrict__ xpack,
                                               const __bf16* __restrict__ Wtp,
                                               __bf16* __restrict__ h0bf) {
    __shared__ __bf16 As[2048];
    __shared__ __bf16 Bs[4096];
    int t = threadIdx.x;
    int lane = t & 63;
    int m = lane & 15, q = lane >> 4;
    int w = t >> 6;
    int wr = (w & 1) * 32;
    int wc = (w >> 1) * 64;
    int r0 = blockIdx.x * 64;
    int h = blockIdx.y;
    int c0 = h * 128;
    const __bf16* ab = xpack + (size_t)blockIdx.x * 65536;
    const __bf16* bb = Wtp + (size_t)h * 4096;

    f32x4 acc[2][4] = {};

#pragma unroll 1
    for (int kk = 0; kk < 32; kk++) {
        async_copy16(bb + (size_t)kk * 8192 + t * 8, &Bs[t * 8]);
        async_copy16(bb + (size_t)kk * 8192 + (t + 256) * 8, &Bs[(t + 256) * 8]);
        async_copy16(ab + (size_t)kk * 2048 + t * 8, &As[t * 8]);
        __syncthreads();

        bf16x8 af[2], bfr[4];
#pragma unroll
        for (int i = 0; i < 2; i++)
            af[i] = *(const bf16x8*)&As[(q * 64 + wr + i * 16 + m) * 8];
#pragma unroll
        for (int jb = 0; jb < 4; jb++)
            bfr[jb] = *(const bf16x8*)&Bs[(q * 128 + wc + jb * 16 + m) * 8];
#pragma unroll
        for (int i = 0; i < 2; i++)
#pragma unroll
            for (int jb = 0; jb < 4; jb++)
                acc[i][jb] = __builtin_amdgcn_mfma_f32_16x16x32_bf16(af[i], bfr[jb], acc[i][jb], 0, 0, 0);
        __syncthreads();
    }

#pragma unroll
    for (int i = 0; i < 2; i++)
#pragma unroll
        for (int jb = 0; jb < 4; jb++)
#pragma unroll
            for (int r = 0; r < 4; r++) {
                int row = r0 + wr + i * 16 + q * 4 + r;
                int col = c0 + wc + jb * 16 + m;
                if (row < NNODES) h0bf[(size_t)row * 256 + col] = (__bf16)acc[i][jb][r];
            }
}

// ---------------- GCN gather (batch-4 MLP) ----------------
__global__ __launch_bounds__(256) void k_gcn_gather(const int* __restrict__ rowptr,
                                                    const int* __restrict__ srcsorted,
                                                    const float* __restrict__ wsorted,
                                                    const __bf16* __restrict__ h0bf,
                                                    const float* __restrict__ dinv,
                                                    const float* __restrict__ bgcn,
                                                    __bf16* __restrict__ hbf) {
    int gid = blockIdx.x * 256 + threadIdx.x;
    int n = gid >> 6, l = gid & 63;
    if (n >= NNODES) return;
    float dn = dinv[n];
    float wn = dn * dn;
    bf16x4 hv = *(const bf16x4*)(h0bf + (size_t)n * 256 + l * 4);
    float4 b = ((const float4*)bgcn)[l];
    float ax = (float)hv[0] * wn + b.x;
    float ay = (float)hv[1] * wn + b.y;
    float az = (float)hv[2] * wn + b.z;
    float aw = (float)hv[3] * wn + b.w;
    int beg = rowptr[n], end = rowptr[n + 1];
    for (int i = beg; i < end; i += 4) {
        int i1 = i + 1 < end ? i + 1 : end - 1;
        int i2 = i + 2 < end ? i + 2 : end - 1;
        int i3 = i + 3 < end ? i + 3 : end - 1;
        int s0 = srcsorted[i], s1 = srcsorted[i1], s2 = srcsorted[i2], s3 = srcsorted[i3];
        float w0 = wsorted[i] * dn;
        float w1 = (i + 1 < end) ? wsorted[i1] * dn : 0.f;
        float w2 = (i + 2 < end) ? wsorted[i2] * dn : 0.f;
        float w3 = (i + 3 < end) ? wsorted[i3] * dn : 0.f;
        bf16x4 v0 = *(const bf16x4*)(h0bf + (size_t)s0 * 256 + l * 4);
        bf16x4 v1 = *(const bf16x4*)(h0bf + (size_t)s1 * 256 + l * 4);
        bf16x4 v2 = *(const bf16x4*)(h0bf + (size_t)s2 * 256 + l * 4);
        bf16x4 v3 = *(const bf16x4*)(h0bf + (size_t)s3 * 256 + l * 4);
        ax += (float)v0[0] * w0 + (float)v1[0] * w1 + (float)v2[0] * w2 + (float)v3[0] * w3;
        ay += (float)v0[1] * w0 + (float)v1[1] * w1 + (float)v2[1] * w2 + (float)v3[1] * w3;
        az += (float)v0[2] * w0 + (float)v1[2] * w1 + (float)v2[2] * w2 + (float)v3[2] * w3;
        aw += (float)v0[3] * w0 + (float)v1[3] * w1 + (float)v2[3] * w2 + (float)v3[3] * w3;
    }
    bf16x4 o;
    o[0] = (__bf16)(ax >= 0.f ? ax : 0.01f * ax);
    o[1] = (__bf16)(ay >= 0.f ? ay : 0.01f * ay);
    o[2] = (__bf16)(az >= 0.f ? az : 0.01f * az);
    o[3] = (__bf16)(aw >= 0.f ? aw : 0.01f * aw);
    *(bf16x4*)(hbf + (size_t)n * 256 + l * 4) = o;
}

// ---------------- GEMM2 ----------------
__global__ __launch_bounds__(256) void k_gemm2(const __bf16* __restrict__ hbf,
                                               const __bf16* __restrict__ Wallt,
                                               const float* __restrict__ ball,
                                               __bf16* __restrict__ qarr,
                                               __bf16* __restrict__ karr,
                                               __bf16* __restrict__ varr,
                                               __bf16* __restrict__ sarr) {
    __shared__ __bf16 As[4096];
    __shared__ __bf16 Bs[4096];
    int t = threadIdx.x;
    int lane = t & 63;
    int m = lane & 15, q = lane >> 4;
    int wave = t >> 6;
    int wr = (wave & 1) * 64;
    int wc = (wave >> 1) * 64;
    int r0 = blockIdx.x * 128;
    int c0 = blockIdx.y * 128;
    __bf16* tbl = (blockIdx.y == 0) ? qarr : (blockIdx.y == 1) ? karr
                : (blockIdx.y == 2) ? varr : sarr;

    const __bf16* asrc[2];
    __bf16* aldst[2];
#pragma unroll
    for (int j = 0; j < 2; j++) {
        int u = j * 256 + t;
        int row = r0 + (u & 127);
        if (row >= NNODES) row = NNODES - 1;
        asrc[j] = hbf + (size_t)row * HMID + (u >> 7) * 8;
        aldst[j] = &As[(size_t)u * 8];
    }
    const __bf16* bsrc[2];
    __bf16* bldst[2];
#pragma unroll
    for (int j = 0; j < 2; j++) {
        int u = j * 256 + t;
        bsrc[j] = Wallt + (size_t)(c0 + (u & 127)) * HMID + (u >> 7) * 8;
        bldst[j] = &Bs[(size_t)u * 8];
    }

    f32x4 acc[4][4] = {};

    for (int k0 = 0; k0 < HMID; k0 += 32) {
#pragma unroll
        for (int j = 0; j < 2; j++) async_copy16(asrc[j] + k0, aldst[j]);
#pragma unroll
        for (int j = 0; j < 2; j++) async_copy16(bsrc[j] + k0, bldst[j]);
        __syncthreads();

        bf16x8 af[4], bfr[4];
#pragma unroll
        for (int i = 0; i < 4; i++) af[i] = *(const bf16x8*)&As[(size_t)(q * 128 + wr + i * 16 + m) * 8];
#pragma unroll
        for (int jb = 0; jb < 4; jb++) bfr[jb] = *(const bf16x8*)&Bs[(size_t)(q * 128 + wc + jb * 16 + m) * 8];
#pragma unroll
        for (int i = 0; i < 4; i++)
#pragma unroll
            for (int jb = 0; jb < 4; jb++)
                acc[i][jb] = __builtin_amdgcn_mfma_f32_16x16x32_bf16(af[i], bfr[jb], acc[i][jb], 0, 0, 0);
        __syncthreads();
    }

#pragma unroll
    for (int jb = 0; jb < 4; jb++) {
        int dcol = wc + jb * 16 + m;
        float bias = ball[c0 + dcol];
#pragma unroll
        for (int i = 0; i < 4; i++)
#pragma unroll
            for (int r = 0; r < 4; r++) {
                int row = r0 + wr + i * 16 + q * 4 + r;
                if (row < NNODES) tbl[(size_t)row * 128 + dcol] = (__bf16)(acc[i][jb][r] + bias);
            }
    }
}

// ---------------- attention scores ----------------
__global__ __launch_bounds__(256) void k_alpha(const int* __restrict__ rowptr,
                                               const int* __restrict__ srcsorted,
                                               const __bf16* __restrict__ qarr,
                                               const __bf16* __restrict__ karr,
                                               float* __restrict__ alpha,
                                               float* __restrict__ part) {
    int n = (blockIdx.x * 256 + threadIdx.x) >> 6;
    int lane = threadIdx.x & 63;
    int g = lane >> 4, l = lane & 15;
    float s1 = 0.f, s2 = 0.f;
    if (n < NNODES) {
        bf16x8 qb = *(const bf16x8*)(qarr + (size_t)n * 128 + l * 8);
        float qf[8];
#pragma unroll
        for (int j = 0; j < 8; j++) qf[j] = (float)qb[j];
        int beg = rowptr[n], end = rowptr[n + 1];
        for (int i = beg + g; i < end; i += 16) {
            int i1 = i + 4 < end ? i + 4 : end - 1;
            int i2 = i + 8 < end ? i + 8 : end - 1;
            int i3 = i + 12 < end ? i + 12 : end - 1;
            int s0 = srcsorted[i], sA = srcsorted[i1], sB = srcsorted[i2], sC = srcsorted[i3];
            bf16x8 k0 = *(const bf16x8*)(karr + (size_t)s0 * 128 + l * 8);
            bf16x8 k1 = *(const bf16x8*)(karr + (size_t)sA * 128 + l * 8);
            bf16x8 k2 = *(const bf16x8*)(karr + (size_t)sB * 128 + l * 8);
            bf16x8 k3 = *(const bf16x8*)(karr + (size_t)sC * 128 + l * 8);
            float d0 = 0.f, d1 = 0.f, d2 = 0.f, d3 = 0.f;
#pragma unroll
            for (int j = 0; j < 8; j++) {
                d0 += qf[j] * (float)k0[j];
                d1 += qf[j] * (float)k1[j];
                d2 += qf[j] * (float)k2[j];
                d3 += qf[j] * (float)k3[j];
            }
#pragma unroll
            for (int off = 1; off < 16; off <<= 1) {
                d0 += __shfl_xor(d0, off, 64);
                d1 += __shfl_xor(d1, off, 64);
                d2 += __shfl_xor(d2, off, 64);
                d3 += __shfl_xor(d3, off, 64);
            }
            if (l == 0) {
                const float sc = 0.08838834764831845f;
                float a0 = d0 * sc;
                alpha[i] = a0; s1 += a0; s2 += a0 * a0;
                if (i + 4 < end)  { float a = d1 * sc; alpha[i + 4]  = a; s1 += a; s2 += a * a; }
                if (i + 8 < end)  { float a = d2 * sc; alpha[i + 8]  = a; s1 += a; s2 += a * a; }
                if (i + 12 < end) { float a = d3 * sc; alpha[i + 12] = a; s1 += a; s2 += a * a; }
            }
        }
    }
#pragma unroll
    for (int off = 1; off < 64; off <<= 1) {
        s1 += __shfl_xor(s1, off, 64);
        s2 += __shfl_xor(s2, off, 64);
    }
    __shared__ float sh[8];
    int wave = threadIdx.x >> 6;
    if ((threadIdx.x & 63) == 0) { sh[wave] = s1; sh[4 + wave] = s2; }
    __syncthreads();
    if (threadIdx.x == 0) {
        part[2 * blockIdx.x]     = sh[0] + sh[1] + sh[2] + sh[3];
        part[2 * blockIdx.x + 1] = sh[4] + sh[5] + sh[6] + sh[7];
    }
}

__global__ __launch_bounds__(1024) void k_stats(const float* __restrict__ part,
                                                float* __restrict__ S) {
    float s1 = 0.f, s2 = 0.f;
    for (int i = threadIdx.x; i < ALPHA_BLOCKS; i += 1024) {
        s1 += part[2 * i];
        s2 += part[2 * i + 1];
    }
#pragma unroll
    for (int off = 1; off < 64; off <<= 1) {
        s1 += __shfl_xor(s1, off, 64);
        s2 += __shfl_xor(s2, off, 64);
    }
    __shared__ float sh1[16], sh2[16];
    int wave = threadIdx.x >> 6;
    if ((threadIdx.x & 63) == 0) { sh1[wave] = s1; sh2[wave] = s2; }
    __syncthreads();
    if (threadIdx.x == 0) {
        float t1 = 0.f, t2 = 0.f;
#pragma unroll
        for (int w = 0; w < 16; w++) { t1 += sh1[w]; t2 += sh2[w]; }
        float mean = t1 / (float)EEDGES;
        float var = (t2 - (float)EEDGES * mean * mean) / (float)(EEDGES - 1);
        float stdv = sqrtf(fmaxf(var, 1e-20f));
        S[2] = mean;
        S[3] = 3.0f / stdv;
    }
}

// ---------------- output gather ----------------
__global__ __launch_bounds__(256) void k_msg_gather(const int* __restrict__ rowptr,
                                                    const int* __restrict__ srcsorted,
                                                    const __bf16* __restrict__ varr,
                                                    const __bf16* __restrict__ sarr,
                                                    const float* __restrict__ alpha,
                                                    const float* __restrict__ S,
                                                    float* __restrict__ out) {
    int n = (blockIdx.x * 256 + threadIdx.x) >> 6;
    int l = threadIdx.x & 63;
    if (n >= NNODES) return;
    float mean = S[2], scl = S[3];
    bf16x2 sb = *(const bf16x2*)(sarr + (size_t)n * 128 + l * 2);
    float ax = (float)sb[0], ay = (float)sb[1];
    int beg = rowptr[n], end = rowptr[n + 1];
    for (int i = beg; i < end; i += 4) {
        int i1 = i + 1 < end ? i + 1 : end - 1;
        int i2 = i + 2 < end ? i + 2 : end - 1;
        int i3 = i + 3 < end ? i + 3 : end - 1;
        int s0 = srcsorted[i], s1 = srcsorted[i1], s2 = srcsorted[i2], s3 = srcsorted[i3];
        float z0 = (alpha[i] - mean) * scl;
        float z1 = (alpha[i1] - mean) * scl;
        float z2 = (alpha[i2] - mean) * scl;
        float z3 = (alpha[i3] - mean) * scl;
        float g0 = 1.0f / (1.0f + __expf(-z0));
        float g1 = (i + 1 < end) ? 1.0f / (1.0f + __expf(-z1)) : 0.f;
        float g2 = (i + 2 < end) ? 1.0f / (1.0f + __expf(-z2)) : 0.f;
        float g3 = (i + 3 < end) ? 1.0f / (1.0f + __expf(-z3)) : 0.f;
        bf16x2 v0 = *(const bf16x2*)(varr + (size_t)s0 * 128 + l * 2);
        bf16x2 v1 = *(const bf16x2*)(varr + (size_t)s1 * 128 + l * 2);
        bf16x2 v2 = *(const bf16x2*)(varr + (size_t)s2 * 128 + l * 2);
        bf16x2 v3 = *(const bf16x2*)(varr + (size_t)s3 * 128 + l * 2);
        ax += (float)v0[0] * g0 + (float)v1[0] * g1 + (float)v2[0] * g2 + (float)v3[0] * g3;
        ay += (float)v0[1] * g0 + (float)v1[1] * g1 + (float)v2[1] * g2 + (float)v3[1] * g3;
    }
    float2 o; o.x = ax; o.y = ay;
    ((float2*)(out + (size_t)n * DOUT))[l] = o;
}

// ---------------- launch ----------------
extern "C" void kernel_launch(void* const* d_in, const int* in_sizes, int n_in,
                              void* d_out, int out_size, void* d_ws, size_t ws_size,
                              hipStream_t stream) {
    const float* x  = (const float*)d_in[0];
    const int* ei   = (const int*)d_in[1];
    const int* srcI = ei;
    const int* dstI = ei + EEDGES;
    const float* Wg = (const float*)d_in[2];
    const float* bg = (const float*)d_in[3];
    const float* Wq = (const float*)d_in[4];  const float* bq = (const float*)d_in[5];
    const float* Wk = (const float*)d_in[6];  const float* bk = (const float*)d_in[7];
    const float* Wv = (const float*)d_in[8];  const float* bv = (const float*)d_in[9];
    const float* Ws = (const float*)d_in[10]; const float* bs = (const float*)d_in[11];
    float* out = (float*)d_out;

    char* wsb = (char*)d_ws;
    size_t off = 0;
    auto alloc = [&](size_t bytes) -> void* {
        void* p = wsb + off;
        off += (bytes + 255) & ~(size_t)255;
        return p;
    };
    int*    cnt    = (int*)alloc((size_t)NNODES * 4);
    int*    rowptr = (int*)alloc((size_t)(NNODES + 1) * 4);
    int*    cursor = (int*)alloc((size_t)NNODES * 4);
    int*    srcst  = (int*)alloc((size_t)EEDGES * 4);
    float*  wsort  = (float*)alloc((size_t)EEDGES * 4);
    float*  dinv   = (float*)alloc((size_t)NNODES * 4);
    float*  S      = (float*)alloc(64);
    float*  part   = (float*)alloc((size_t)ALPHA_BLOCKS * 2 * 4);
    __bf16* xpack  = (__bf16*)alloc(XPACK_ELEMS * 2);
    __bf16* Wtp    = (__bf16*)alloc((size_t)32 * 8192 * 2);
    __bf16* Wallt  = (__bf16*)alloc((size_t)512 * HMID * 2);
    float*  ball   = (float*)alloc(512 * 4);
    __bf16* h0bf   = (__bf16*)alloc((size_t)NNODES * HMID * 2);
    __bf16* hbf    = (__bf16*)alloc((size_t)NNODES * HMID * 2);
    __bf16* qarr   = (__bf16*)alloc((size_t)NNODES * 128 * 2);
    __bf16* karr   = (__bf16*)alloc((size_t)NNODES * 128 * 2);
    __bf16* varr   = (__bf16*)alloc((size_t)NNODES * 128 * 2);
    __bf16* sarr   = (__bf16*)alloc((size_t)NNODES * 128 * 2);
    float*  alphab = (float*)alloc((size_t)EEDGES * 4);
    if (off > ws_size) return;

    k_pack_x<<<RTILES * 16, 256, 0, stream>>>(x, xpack);  // 313*64 slots / 4 per block
    k_pack_w<<<(FIN * HMID + 255) / 256, 256, 0, stream>>>(Wg, Wtp);
    dim3 gw((HMID * DOUT + 255) / 256, 4);
    k_prep_watt<<<gw, 256, 0, stream>>>(Wq, Wk, Wv, Ws, bq, bk, bv, bs, Wallt, ball);

    k_init<<<(NNODES + 255) / 256, 256, 0, stream>>>(cnt, S);
    k_count<<<(EEDGES + 255) / 256, 256, 0, stream>>>(dstI, cnt);
    k_dinv<<<(NNODES + 255) / 256, 256, 0, stream>>>(cnt, dinv, cursor);
    k_scan<<<1, 1024, 0, stream>>>(cnt, rowptr);
    k_fill<<<(EEDGES + 255) / 256, 256, 0, stream>>>(srcI, dstI, rowptr, cursor, dinv, srcst, wsort);

    dim3 g1(RTILES, 2);
    k_gemm1<<<g1, 256, 0, stream>>>(xpack, Wtp, h0bf);

    k_gcn_gather<<<(NNODES * 64 + 255) / 256, 256, 0, stream>>>(rowptr, srcst, wsort, h0bf, dinv, bg, hbf);

    dim3 g2((NNODES + 127) / 128, 4);
    k_gemm2<<<g2, 256, 0, stream>>>(hbf, Wallt, ball, qarr, karr, varr, sarr);

    k_alpha<<<ALPHA_BLOCKS, 256, 0, stream>>>(rowptr, srcst, qarr, karr, alphab, part);
    k_stats<<<1, 1024, 0, stream>>>(part, S);

    k_msg_gather<<<(NNODES * 64 + 255) / 256, 256, 0, stream>>>(rowptr, srcst, varr, sarr, alphab, S, out);
}

// Round 9
// 325.978 us; speedup vs baseline: 1.0857x; 1.0431x over previous
//
#include <hip/hip_runtime.h>
#include <hip/hip_bf16.h>

#define NNODES 20000
#define EEDGES 320000
#define FIN 1024
#define HMID 256
#define DOUT 128
#define ALPHA_BLOCKS ((NNODES + 3) / 4)
#define RTILES 313

typedef __bf16 bf16x8 __attribute__((ext_vector_type(8)));
typedef __bf16 bf16x4 __attribute__((ext_vector_type(4)));
typedef __bf16 bf16x2 __attribute__((ext_vector_type(2)));
typedef float f32x4 __attribute__((ext_vector_type(4)));

typedef const __attribute__((address_space(1))) void* gas_ptr;
typedef __attribute__((address_space(3))) void* las_ptr;
__device__ __forceinline__ void async_copy16(const void* g, void* l) {
    __builtin_amdgcn_global_load_lds((gas_ptr)g, (las_ptr)l, 16, 0, 0);
}

// ---------------- weight packing ----------------
// Wtp: for iter kk (32 k), col-half h (128 cols): 512 16B-units; unit u = kq*128 + (col&127)
// holds W_gcn[kk*32+kq*8+j][col], j in 0..8. Elem addr: ((kk*2+h)*512 + u)*8 + j.
__global__ void k_pack_w(const float* __restrict__ W, __bf16* __restrict__ Wtp) {
    int tid = blockIdx.x * 256 + threadIdx.x;
    if (tid >= FIN * HMID) return;
    int k = tid >> 8;
    int n = tid & 255;
    int kk = k >> 5, kq = (k >> 3) & 3, j = k & 7;
    int h = n >> 7;
    int u = kq * 128 + (n & 127);
    Wtp[((size_t)(kk * 2 + h) * 512 + u) * 8 + j] = (__bf16)W[tid];
}

__global__ void k_prep_watt(const float* __restrict__ Wq, const float* __restrict__ Wk,
                            const float* __restrict__ Wv, const float* __restrict__ Ws,
                            const float* __restrict__ bq, const float* __restrict__ bk,
                            const float* __restrict__ bv, const float* __restrict__ bs,
                            __bf16* __restrict__ Wallt, float* __restrict__ ball) {
    int g = blockIdx.y;
    const float* W = (g == 0) ? Wq : (g == 1) ? Wk : (g == 2) ? Wv : Ws;
    int tid = blockIdx.x * 256 + threadIdx.x;
    if (tid < HMID * DOUT) {
        int k = tid >> 7;
        int n = tid & 127;
        Wallt[(size_t)(g * DOUT + n) * HMID + k] = (__bf16)W[tid];
    }
    if (tid < DOUT) {
        const float* b = (g == 0) ? bq : (g == 1) ? bk : (g == 2) ? bv : bs;
        ball[g * DOUT + tid] = b[tid];
    }
}

// ---------------- CSR build ----------------
__global__ void k_init(int* __restrict__ cnt, float* __restrict__ S) {
    int i = blockIdx.x * 256 + threadIdx.x;
    if (i < NNODES) cnt[i] = 0;
    if (i < 16) S[i] = 0.0f;
}

__global__ void k_count(const int* __restrict__ dst, int* __restrict__ cnt) {
    int e = blockIdx.x * 256 + threadIdx.x;
    if (e < EEDGES) atomicAdd(&cnt[dst[e]], 1);
}

__global__ void k_dinv(const int* __restrict__ cnt, float* __restrict__ dinv,
                       int* __restrict__ cursor) {
    int i = blockIdx.x * 256 + threadIdx.x;
    if (i < NNODES) {
        dinv[i] = rsqrtf((float)cnt[i] + 1.0f);
        cursor[i] = 0;
    }
}

__global__ __launch_bounds__(1024) void k_scan(const int* __restrict__ cnt,
                                               int* __restrict__ rowptr) {
    __shared__ int sh[1024];
    int t = threadIdx.x;
    int base = t * 20;
    int local[20];
    int sum = 0;
#pragma unroll
    for (int j = 0; j < 20; j++) {
        int i = base + j;
        int v = (i < NNODES) ? cnt[i] : 0;
        local[j] = sum;
        sum += v;
    }
    sh[t] = sum;
    __syncthreads();
    for (int off = 1; off < 1024; off <<= 1) {
        int v = (t >= off) ? sh[t - off] : 0;
        __syncthreads();
        sh[t] += v;
        __syncthreads();
    }
    int prev = (t > 0) ? sh[t - 1] : 0;
#pragma unroll
    for (int j = 0; j < 20; j++) {
        int i = base + j;
        if (i < NNODES) rowptr[i] = prev + local[j];
    }
    if (t == 1023) rowptr[NNODES] = sh[1023];
}

__global__ void k_fill(const int* __restrict__ src, const int* __restrict__ dst,
                       const int* __restrict__ rowptr, int* __restrict__ cursor,
                       const float* __restrict__ dinv,
                       int* __restrict__ srcsorted, float* __restrict__ wsorted) {
    int e = blockIdx.x * 256 + threadIdx.x;
    if (e >= EEDGES) return;
    int d = dst[e];
    int s = src[e];
    int pos = atomicAdd(&cursor[d], 1);
    int w = rowptr[d] + pos;
    srcsorted[w] = s;
    wsorted[w] = dinv[s];
}

// ---------------- GEMM1: h0bf = bf16(x @ W_gcn), fused transpose staging ----------------
// 64x128 tile, grid (313,2). A: each thread reads 32B contiguous fp32 of one row,
// converts, ds_write_b128 into [kq*64+r] fragment layout (reg-double-buffered loads).
// B: packed Wtp via global_load_lds (wave-contiguous).
__global__ __launch_bounds__(256) void k_gemm1(const float* __restrict__ x,
                                               const __bf16* __restrict__ Wtp,
                                               __bf16* __restrict__ h0bf) {
    __shared__ __bf16 As[2048];   // 4 KB: unit u = kq*64 + r
    __shared__ __bf16 Bs[4096];   // 8 KB: unit u = kq*128 + c
    int t = threadIdx.x;
    int lane = t & 63;
    int m = lane & 15, q = lane >> 4;
    int w = t >> 6;
    int wr = (w & 1) * 32;
    int wc = (w >> 1) * 64;
    int r0 = blockIdx.x * 64;
    int h = blockIdx.y;
    int c0 = h * 128;

    int ar = r0 + (t >> 2);
    if (ar >= NNODES) ar = NNODES - 1;
    const float* ap = x + (size_t)ar * FIN + (t & 3) * 8;
    __bf16* awr = &As[((t & 3) * 64 + (t >> 2)) * 8];
    const __bf16* bb = Wtp + (size_t)h * 4096;

    f32x4 acc[2][4] = {};

    float4 a0 = *(const float4*)(ap);
    float4 a1 = *(const float4*)(ap + 4);

#pragma unroll 1
    for (int kk = 0; kk < 32; kk++) {
        async_copy16(bb + (size_t)kk * 8192 + t * 8, &Bs[t * 8]);
        async_copy16(bb + (size_t)kk * 8192 + (t + 256) * 8, &Bs[(t + 256) * 8]);
        bf16x8 av;
        av[0] = (__bf16)a0.x; av[1] = (__bf16)a0.y; av[2] = (__bf16)a0.z; av[3] = (__bf16)a0.w;
        av[4] = (__bf16)a1.x; av[5] = (__bf16)a1.y; av[6] = (__bf16)a1.z; av[7] = (__bf16)a1.w;
        *(bf16x8*)awr = av;
        if (kk + 1 < 32) {
            a0 = *(const float4*)(ap + (kk + 1) * 32);
            a1 = *(const float4*)(ap + (kk + 1) * 32 + 4);
        }
        __syncthreads();

        bf16x8 af[2], bfr[4];
#pragma unroll
        for (int i = 0; i < 2; i++)
            af[i] = *(const bf16x8*)&As[(q * 64 + wr + i * 16 + m) * 8];
#pragma unroll
        for (int jb = 0; jb < 4; jb++)
            bfr[jb] = *(const bf16x8*)&Bs[(q * 128 + wc + jb * 16 + m) * 8];
#pragma unroll
        for (int i = 0; i < 2; i++)
#pragma unroll
            for (int jb = 0; jb < 4; jb++)
                acc[i][jb] = __builtin_amdgcn_mfma_f32_16x16x32_bf16(af[i], bfr[jb], acc[i][jb], 0, 0, 0);
        __syncthreads();
    }

#pragma unroll
    for (int i = 0; i < 2; i++)
#pragma unroll
        for (int jb = 0; jb < 4; jb++)
#pragma unroll
            for (int r = 0; r < 4; r++) {
                int row = r0 + wr + i * 16 + q * 4 + r;
                int col = c0 + wc + jb * 16 + m;
                if (row < NNODES) h0bf[(size_t)row * 256 + col] = (__bf16)acc[i][jb][r];
            }
}

// ---------------- GCN gather (batch-4 MLP) ----------------
__global__ __launch_bounds__(256) void k_gcn_gather(const int* __restrict__ rowptr,
                                                    const int* __restrict__ srcsorted,
                                                    const float* __restrict__ wsorted,
                                                    const __bf16* __restrict__ h0bf,
                                                    const float* __restrict__ dinv,
                                                    const float* __restrict__ bgcn,
                                                    __bf16* __restrict__ hbf) {
    int gid = blockIdx.x * 256 + threadIdx.x;
    int n = gid >> 6, l = gid & 63;
    if (n >= NNODES) return;
    float dn = dinv[n];
    float wn = dn * dn;
    bf16x4 hv = *(const bf16x4*)(h0bf + (size_t)n * 256 + l * 4);
    float4 b = ((const float4*)bgcn)[l];
    float ax = (float)hv[0] * wn + b.x;
    float ay = (float)hv[1] * wn + b.y;
    float az = (float)hv[2] * wn + b.z;
    float aw = (float)hv[3] * wn + b.w;
    int beg = rowptr[n], end = rowptr[n + 1];
    for (int i = beg; i < end; i += 4) {
        int i1 = i + 1 < end ? i + 1 : end - 1;
        int i2 = i + 2 < end ? i + 2 : end - 1;
        int i3 = i + 3 < end ? i + 3 : end - 1;
        int s0 = srcsorted[i], s1 = srcsorted[i1], s2 = srcsorted[i2], s3 = srcsorted[i3];
        float w0 = wsorted[i] * dn;
        float w1 = (i + 1 < end) ? wsorted[i1] * dn : 0.f;
        float w2 = (i + 2 < end) ? wsorted[i2] * dn : 0.f;
        float w3 = (i + 3 < end) ? wsorted[i3] * dn : 0.f;
        bf16x4 v0 = *(const bf16x4*)(h0bf + (size_t)s0 * 256 + l * 4);
        bf16x4 v1 = *(const bf16x4*)(h0bf + (size_t)s1 * 256 + l * 4);
        bf16x4 v2 = *(const bf16x4*)(h0bf + (size_t)s2 * 256 + l * 4);
        bf16x4 v3 = *(const bf16x4*)(h0bf + (size_t)s3 * 256 + l * 4);
        ax += (float)v0[0] * w0 + (float)v1[0] * w1 + (float)v2[0] * w2 + (float)v3[0] * w3;
        ay += (float)v0[1] * w0 + (float)v1[1] * w1 + (float)v2[1] * w2 + (float)v3[1] * w3;
        az += (float)v0[2] * w0 + (float)v1[2] * w1 + (float)v2[2] * w2 + (float)v3[2] * w3;
        aw += (float)v0[3] * w0 + (float)v1[3] * w1 + (float)v2[3] * w2 + (float)v3[3] * w3;
    }
    bf16x4 o;
    o[0] = (__bf16)(ax >= 0.f ? ax : 0.01f * ax);
    o[1] = (__bf16)(ay >= 0.f ? ay : 0.01f * ay);
    o[2] = (__bf16)(az >= 0.f ? az : 0.01f * az);
    o[3] = (__bf16)(aw >= 0.f ? aw : 0.01f * aw);
    *(bf16x4*)(hbf + (size_t)n * 256 + l * 4) = o;
}

// ---------------- GEMM2 ----------------
__global__ __launch_bounds__(256) void k_gemm2(const __bf16* __restrict__ hbf,
                                               const __bf16* __restrict__ Wallt,
                                               const float* __restrict__ ball,
                                               __bf16* __restrict__ qarr,
                                               __bf16* __restrict__ karr,
                                               __bf16* __restrict__ varr,
                                               __bf16* __restrict__ sarr) {
    __shared__ __bf16 As[4096];
    __shared__ __bf16 Bs[4096];
    int t = threadIdx.x;
    int lane = t & 63;
    int m = lane & 15, q = lane >> 4;
    int wave = t >> 6;
    int wr = (wave & 1) * 64;
    int wc = (wave >> 1) * 64;
    int r0 = blockIdx.x * 128;
    int c0 = blockIdx.y * 128;
    __bf16* tbl = (blockIdx.y == 0) ? qarr : (blockIdx.y == 1) ? karr
                : (blockIdx.y == 2) ? varr : sarr;

    const __bf16* asrc[2];
    __bf16* aldst[2];
#pragma unroll
    for (int j = 0; j < 2; j++) {
        int u = j * 256 + t;
        int row = r0 + (u & 127);
        if (row >= NNODES) row = NNODES - 1;
        asrc[j] = hbf + (size_t)row * HMID + (u >> 7) * 8;
        aldst[j] = &As[(size_t)u * 8];
    }
    const __bf16* bsrc[2];
    __bf16* bldst[2];
#pragma unroll
    for (int j = 0; j < 2; j++) {
        int u = j * 256 + t;
        bsrc[j] = Wallt + (size_t)(c0 + (u & 127)) * HMID + (u >> 7) * 8;
        bldst[j] = &Bs[(size_t)u * 8];
    }

    f32x4 acc[4][4] = {};

    for (int k0 = 0; k0 < HMID; k0 += 32) {
#pragma unroll
        for (int j = 0; j < 2; j++) async_copy16(asrc[j] + k0, aldst[j]);
#pragma unroll
        for (int j = 0; j < 2; j++) async_copy16(bsrc[j] + k0, bldst[j]);
        __syncthreads();

        bf16x8 af[4], bfr[4];
#pragma unroll
        for (int i = 0; i < 4; i++) af[i] = *(const bf16x8*)&As[(size_t)(q * 128 + wr + i * 16 + m) * 8];
#pragma unroll
        for (int jb = 0; jb < 4; jb++) bfr[jb] = *(const bf16x8*)&Bs[(size_t)(q * 128 + wc + jb * 16 + m) * 8];
#pragma unroll
        for (int i = 0; i < 4; i++)
#pragma unroll
            for (int jb = 0; jb < 4; jb++)
                acc[i][jb] = __builtin_amdgcn_mfma_f32_16x16x32_bf16(af[i], bfr[jb], acc[i][jb], 0, 0, 0);
        __syncthreads();
    }

#pragma unroll
    for (int jb = 0; jb < 4; jb++) {
        int dcol = wc + jb * 16 + m;
        float bias = ball[c0 + dcol];
#pragma unroll
        for (int i = 0; i < 4; i++)
#pragma unroll
            for (int r = 0; r < 4; r++) {
                int row = r0 + wr + i * 16 + q * 4 + r;
                if (row < NNODES) tbl[(size_t)row * 128 + dcol] = (__bf16)(acc[i][jb][r] + bias);
            }
    }
}

// ---------------- attention scores ----------------
__global__ __launch_bounds__(256) void k_alpha(const int* __restrict__ rowptr,
                                               const int* __restrict__ srcsorted,
                                               const __bf16* __restrict__ qarr,
                                               const __bf16* __restrict__ karr,
                                               float* __restrict__ alpha,
                                               float* __restrict__ part) {
    int n = (blockIdx.x * 256 + threadIdx.x) >> 6;
    int lane = threadIdx.x & 63;
    int g = lane >> 4, l = lane & 15;
    float s1 = 0.f, s2 = 0.f;
    if (n < NNODES) {
        bf16x8 qb = *(const bf16x8*)(qarr + (size_t)n * 128 + l * 8);
        float qf[8];
#pragma unroll
        for (int j = 0; j < 8; j++) qf[j] = (float)qb[j];
        int beg = rowptr[n], end = rowptr[n + 1];
        for (int i = beg + g; i < end; i += 16) {
            int i1 = i + 4 < end ? i + 4 : end - 1;
            int i2 = i + 8 < end ? i + 8 : end - 1;
            int i3 = i + 12 < end ? i + 12 : end - 1;
            int s0 = srcsorted[i], sA = srcsorted[i1], sB = srcsorted[i2], sC = srcsorted[i3];
            bf16x8 k0 = *(const bf16x8*)(karr + (size_t)s0 * 128 + l * 8);
            bf16x8 k1 = *(const bf16x8*)(karr + (size_t)sA * 128 + l * 8);
            bf16x8 k2 = *(const bf16x8*)(karr + (size_t)sB * 128 + l * 8);
            bf16x8 k3 = *(const bf16x8*)(karr + (size_t)sC * 128 + l * 8);
            float d0 = 0.f, d1 = 0.f, d2 = 0.f, d3 = 0.f;
#pragma unroll
            for (int j = 0; j < 8; j++) {
                d0 += qf[j] * (float)k0[j];
                d1 += qf[j] * (float)k1[j];
                d2 += qf[j] * (float)k2[j];
                d3 += qf[j] * (float)k3[j];
            }
#pragma unroll
            for (int off = 1; off < 16; off <<= 1) {
                d0 += __shfl_xor(d0, off, 64);
                d1 += __shfl_xor(d1, off, 64);
                d2 += __shfl_xor(d2, off, 64);
                d3 += __shfl_xor(d3, off, 64);
            }
            if (l == 0) {
                const float sc = 0.08838834764831845f;
                float a0 = d0 * sc;
                alpha[i] = a0; s1 += a0; s2 += a0 * a0;
                if (i + 4 < end)  { float a = d1 * sc; alpha[i + 4]  = a; s1 += a; s2 += a * a; }
                if (i + 8 < end)  { float a = d2 * sc; alpha[i + 8]  = a; s1 += a; s2 += a * a; }
                if (i + 12 < end) { float a = d3 * sc; alpha[i + 12] = a; s1 += a; s2 += a * a; }
            }
        }
    }
#pragma unroll
    for (int off = 1; off < 64; off <<= 1) {
        s1 += __shfl_xor(s1, off, 64);
        s2 += __shfl_xor(s2, off, 64);
    }
    __shared__ float sh[8];
    int wave = threadIdx.x >> 6;
    if ((threadIdx.x & 63) == 0) { sh[wave] = s1; sh[4 + wave] = s2; }
    __syncthreads();
    if (threadIdx.x == 0) {
        part[2 * blockIdx.x]     = sh[0] + sh[1] + sh[2] + sh[3];
        part[2 * blockIdx.x + 1] = sh[4] + sh[5] + sh[6] + sh[7];
    }
}

__global__ __launch_bounds__(1024) void k_stats(const float* __restrict__ part,
                                                float* __restrict__ S) {
    float s1 = 0.f, s2 = 0.f;
    for (int i = threadIdx.x; i < ALPHA_BLOCKS; i += 1024) {
        s1 += part[2 * i];
        s2 += part[2 * i + 1];
    }
#pragma unroll
    for (int off = 1; off < 64; off <<= 1) {
        s1 += __shfl_xor(s1, off, 64);
        s2 += __shfl_xor(s2, off, 64);
    }
    __shared__ float sh1[16], sh2[16];
    int wave = threadIdx.x >> 6;
    if ((threadIdx.x & 63) == 0) { sh1[wave] = s1; sh2[wave] = s2; }
    __syncthreads();
    if (threadIdx.x == 0) {
        float t1 = 0.f, t2 = 0.f;
#pragma unroll
        for (int w = 0; w < 16; w++) { t1 += sh1[w]; t2 += sh2[w]; }
        float mean = t1 / (float)EEDGES;
        float var = (t2 - (float)EEDGES * mean * mean) / (float)(EEDGES - 1);
        float stdv = sqrtf(fmaxf(var, 1e-20f));
        S[2] = mean;
        S[3] = 3.0f / stdv;
    }
}

// ---------------- output gather ----------------
__global__ __launch_bounds__(256) void k_msg_gather(const int* __restrict__ rowptr,
                                                    const int* __restrict__ srcsorted,
                                                    const __bf16* __restrict__ varr,
                                                    const __bf16* __restrict__ sarr,
                                                    const float* __restrict__ alpha,
                                                    const float* __restrict__ S,
                                                    float* __restrict__ out) {
    int n = (blockIdx.x * 256 + threadIdx.x) >> 6;
    int l = threadIdx.x & 63;
    if (n >= NNODES) return;
    float mean = S[2], scl = S[3];
    bf16x2 sb = *(const bf16x2*)(sarr + (size_t)n * 128 + l * 2);
    float ax = (float)sb[0], ay = (float)sb[1];
    int beg = rowptr[n], end = rowptr[n + 1];
    for (int i = beg; i < end; i += 4) {
        int i1 = i + 1 < end ? i + 1 : end - 1;
        int i2 = i + 2 < end ? i + 2 : end - 1;
        int i3 = i + 3 < end ? i + 3 : end - 1;
        int s0 = srcsorted[i], s1 = srcsorted[i1], s2 = srcsorted[i2], s3 = srcsorted[i3];
        float z0 = (alpha[i] - mean) * scl;
        float z1 = (alpha[i1] - mean) * scl;
        float z2 = (alpha[i2] - mean) * scl;
        float z3 = (alpha[i3] - mean) * scl;
        float g0 = 1.0f / (1.0f + __expf(-z0));
        float g1 = (i + 1 < end) ? 1.0f / (1.0f + __expf(-z1)) : 0.f;
        float g2 = (i + 2 < end) ? 1.0f / (1.0f + __expf(-z2)) : 0.f;
        float g3 = (i + 3 < end) ? 1.0f / (1.0f + __expf(-z3)) : 0.f;
        bf16x2 v0 = *(const bf16x2*)(varr + (size_t)s0 * 128 + l * 2);
        bf16x2 v1 = *(const bf16x2*)(varr + (size_t)s1 * 128 + l * 2);
        bf16x2 v2 = *(const bf16x2*)(varr + (size_t)s2 * 128 + l * 2);
        bf16x2 v3 = *(const bf16x2*)(varr + (size_t)s3 * 128 + l * 2);
        ax += (float)v0[0] * g0 + (float)v1[0] * g1 + (float)v2[0] * g2 + (float)v3[0] * g3;
        ay += (float)v0[1] * g0 + (float)v1[1] * g1 + (float)v2[1] * g2 + (float)v3[1] * g3;
    }
    float2 o; o.x = ax; o.y = ay;
    ((float2*)(out + (size_t)n * DOUT))[l] = o;
}

// ---------------- launch ----------------
extern "C" void kernel_launch(void* const* d_in, const int* in_sizes, int n_in,
                              void* d_out, int out_size, void* d_ws, size_t ws_size,
                              hipStream_t stream) {
    const float* x  = (const float*)d_in[0];
    const int* ei   = (const int*)d_in[1];
    const int* srcI = ei;
    const int* dstI = ei + EEDGES;
    const float* Wg = (const float*)d_in[2];
    const float* bg = (const float*)d_in[3];
    const float* Wq = (const float*)d_in[4];  const float* bq = (const float*)d_in[5];
    const float* Wk = (const float*)d_in[6];  const float* bk = (const float*)d_in[7];
    const float* Wv = (const float*)d_in[8];  const float* bv = (const float*)d_in[9];
    const float* Ws = (const float*)d_in[10]; const float* bs = (const float*)d_in[11];
    float* out = (float*)d_out;

    char* wsb = (char*)d_ws;
    size_t off = 0;
    auto alloc = [&](size_t bytes) -> void* {
        void* p = wsb + off;
        off += (bytes + 255) & ~(size_t)255;
        return p;
    };
    int*    cnt    = (int*)alloc((size_t)NNODES * 4);
    int*    rowptr = (int*)alloc((size_t)(NNODES + 1) * 4);
    int*    cursor = (int*)alloc((size_t)NNODES * 4);
    int*    srcst  = (int*)alloc((size_t)EEDGES * 4);
    float*  wsort  = (float*)alloc((size_t)EEDGES * 4);
    float*  dinv   = (float*)alloc((size_t)NNODES * 4);
    float*  S      = (float*)alloc(64);
    float*  part   = (float*)alloc((size_t)ALPHA_BLOCKS * 2 * 4);
    __bf16* Wtp    = (__bf16*)alloc((size_t)32 * 8192 * 2);
    __bf16* Wallt  = (__bf16*)alloc((size_t)512 * HMID * 2);
    float*  ball   = (float*)alloc(512 * 4);
    __bf16* h0bf   = (__bf16*)alloc((size_t)NNODES * HMID * 2);
    __bf16* hbf    = (__bf16*)alloc((size_t)NNODES * HMID * 2);
    __bf16* qarr   = (__bf16*)alloc((size_t)NNODES * 128 * 2);
    __bf16* karr   = (__bf16*)alloc((size_t)NNODES * 128 * 2);
    __bf16* varr   = (__bf16*)alloc((size_t)NNODES * 128 * 2);
    __bf16* sarr   = (__bf16*)alloc((size_t)NNODES * 128 * 2);
    float*  alphab = (float*)alloc((size_t)EEDGES * 4);
    if (off > ws_size) return;

    k_pack_w<<<(FIN * HMID + 255) / 256, 256, 0, stream>>>(Wg, Wtp);
    dim3 gw((HMID * DOUT + 255) / 256, 4);
    k_prep_watt<<<gw, 256, 0, stream>>>(Wq, Wk, Wv, Ws, bq, bk, bv, bs, Wallt, ball);

    k_init<<<(NNODES + 255) / 256, 256, 0, stream>>>(cnt, S);
    k_count<<<(EEDGES + 255) / 256, 256, 0, stream>>>(dstI, cnt);
    k_dinv<<<(NNODES + 255) / 256, 256, 0, stream>>>(cnt, dinv, cursor);
    k_scan<<<1, 1024, 0, stream>>>(cnt, rowptr);
    k_fill<<<(EEDGES + 255) / 256, 256, 0, stream>>>(srcI, dstI, rowptr, cursor, dinv, srcst, wsort);

    dim3 g1(RTILES, 2);
    k_gemm1<<<g1, 256, 0, stream>>>(x, Wtp, h0bf);

    k_gcn_gather<<<(NNODES * 64 + 255) / 256, 256, 0, stream>>>(rowptr, srcst, wsort, h0bf, dinv, bg, hbf);

    dim3 g2((NNODES + 127) / 128, 4);
    k_gemm2<<<g2, 256, 0, stream>>>(hbf, Wallt, ball, qarr, karr, varr, sarr);

    k_alpha<<<ALPHA_BLOCKS, 256, 0, stream>>>(rowptr, srcst, qarr, karr, alphab, part);
    k_stats<<<1, 1024, 0, stream>>>(part, S);

    k_msg_gather<<<(NNODES * 64 + 255) / 256, 256, 0, stream>>>(rowptr, srcst, varr, sarr, alphab, S, out);
}